// Round 8
// baseline (519.489 us; speedup 1.0000x reference)
//
#include <hip/hip_runtime.h>
#include <hip/hip_bf16.h>
#include <math.h>

#define N_NODES 50000
#define N_EDGES 800000
#define IN_DIM  128
#define HC_DIM  128
#define HID_C   32
#define SCAN_NB 196   // ceil(50000/256)
#define LOG2E   1.4426950408889634f
#define NODE_HALF 25000   // k_node: 6250 blocks x 4 waves = 25000 waves, 2 nodes each

typedef __attribute__((ext_vector_type(8))) short short8;   // 8 bf16 = 4 VGPR (MFMA A/B frag)
typedef __attribute__((ext_vector_type(4))) float f32x4;    // MFMA C/D frag
typedef _Float16 hf8 __attribute__((ext_vector_type(8)));
typedef unsigned int uint4v __attribute__((ext_vector_type(4)));

__device__ __forceinline__ float gelu_f(float x){
    return 0.5f*x*(1.0f + erff(x*0.7071067811865475f));
}

// fp32 -> (hi, lo) bf16 split: hi = rn(f), lo = rn(f - hi). hi+lo ~ fp32 (2^-17 rel).
__device__ __forceinline__ void split2(float f, short& h, short& l){
    __hip_bfloat16 bh = __float2bfloat16(f);
    float r = f - __bfloat162float(bh);
    __hip_bfloat16 blo = __float2bfloat16(r);
    h = *reinterpret_cast<short*>(&bh);
    l = *reinterpret_cast<short*>(&blo);
}
__device__ __forceinline__ unsigned short f2h(float f){
    _Float16 h = (_Float16)f;
    return __builtin_bit_cast(unsigned short, h);
}
__device__ __forceinline__ float bf2f(unsigned short u){
    return __uint_as_float(((unsigned)u)<<16);
}

// ---------------- CSR build ----------------
__global__ __launch_bounds__(256) void k_count(const int* __restrict__ dst, int* __restrict__ cnt,
                                               int* __restrict__ rank){
    int b = blockIdx.x*1024 + threadIdx.x;
    #pragma unroll
    for(int i=0;i<4;i++){
        int e = b + i*256;
        if(e < N_EDGES) rank[e] = atomicAdd(&cnt[dst[e]], 1);
    }
}

__global__ __launch_bounds__(256) void k_scan1(const int* __restrict__ cnt, int* __restrict__ rowptr,
                                               int* __restrict__ part){
    __shared__ int sh[256];
    int t=threadIdx.x; int i=blockIdx.x*256+t;
    int v = (i<N_NODES)? cnt[i] : 0;
    sh[t]=v; __syncthreads();
    for(int off=1; off<256; off<<=1){
        int y = (t>=off)? sh[t-off] : 0;
        __syncthreads();
        sh[t] += y;
        __syncthreads();
    }
    if(i<N_NODES) rowptr[i] = sh[t]-v;
    if(t==255) part[blockIdx.x] = sh[255];
}

__global__ __launch_bounds__(256) void k_scan2(int* __restrict__ part){
    __shared__ int sh[256];
    int t=threadIdx.x;
    int v = (t<SCAN_NB)? part[t] : 0;
    sh[t]=v; __syncthreads();
    for(int off=1; off<256; off<<=1){
        int y=(t>=off)? sh[t-off]:0;
        __syncthreads();
        sh[t]+=y;
        __syncthreads();
    }
    if(t<SCAN_NB) part[t] = sh[t]-v;
}

__global__ __launch_bounds__(256) void k_scan3(int* __restrict__ rowptr, const int* __restrict__ part){
    int t=threadIdx.x; int i=blockIdx.x*256+t;
    if(i<N_NODES) rowptr[i] += part[blockIdx.x];
    if(i==0) rowptr[N_NODES]=N_EDGES;
}

__global__ __launch_bounds__(256) void k_fill(const int* __restrict__ src, const int* __restrict__ dst,
                                              const int* __restrict__ rowptr, const int* __restrict__ rank,
                                              int* __restrict__ col){
    int b = blockIdx.x*1024 + threadIdx.x;
    #pragma unroll
    for(int i=0;i<4;i++){
        int e = b + i*256;
        if(e < N_EDGES) col[rowptr[dst[e]] + rank[e]] = src[e];
    }
}

// Pre-split all 7 weight matrices into transposed hi/lo bf16 [n][k].
__global__ __launch_bounds__(256) void k_splitW(const float* __restrict__ W0, const float* __restrict__ W1,
                                                const float* __restrict__ W2, const float* __restrict__ W3,
                                                const float* __restrict__ W4, const float* __restrict__ W5,
                                                const float* __restrict__ W6, short* __restrict__ WT){
    int bx = blockIdx.x;
    int m, kc;
    if(bx < 2){ m = bx; kc = 0; }
    else { m = 2 + (bx-2)/4; kc = (bx-2)&3; }
    const float* src; int K; size_t off;
    switch(m){
        case 0: src=W0; K=32;  off=0;      break;
        case 1: src=W1; K=32;  off=8192;   break;
        case 2: src=W2; K=128; off=16384;  break;
        case 3: src=W3; K=128; off=49152;  break;
        case 4: src=W4; K=128; off=81920;  break;
        case 5: src=W5; K=128; off=114688; break;
        default:src=W6; K=128; off=147456; break;
    }
    short* hi = WT + off;
    short* lo = hi + (size_t)K*HC_DIM;
    #pragma unroll
    for(int i=0;i<16;i++){
        int idx = threadIdx.x + i*256;
        int k = kc*32 + (idx>>7);
        int n = idx & 127;
        float f = src[(size_t)k*HC_DIM + n];
        short h,l; split2(f,h,l);
        hi[(size_t)n*K + k] = h;
        lo[(size_t)n*K + k] = l;
    }
}

// h[N,32] = gelu(x[N,128] @ Win[128,32] + bin), emitted as bf16 hi/lo only.
__global__ __launch_bounds__(256) void k_gemm_in(const float* __restrict__ x, const float* __restrict__ W,
                                                 const float* __restrict__ b,
                                                 short* __restrict__ hhi, short* __restrict__ hlo){
    int id = blockIdx.x*256+threadIdx.x;
    int r = id>>5, c = id&31;
    const float4* x4 = (const float4*)(x + (size_t)r*IN_DIM);
    float acc=0.f;
    #pragma unroll 8
    for(int k=0;k<IN_DIM/4;k++){
        float4 xv = x4[k];
        acc = fmaf(xv.x, W[(4*k  )*HID_C+c], acc);
        acc = fmaf(xv.y, W[(4*k+1)*HID_C+c], acc);
        acc = fmaf(xv.z, W[(4*k+2)*HID_C+c], acc);
        acc = fmaf(xv.w, W[(4*k+3)*HID_C+c], acc);
    }
    float v = gelu_f(acc + b[c]);
    short hh,ll; split2(v,hh,ll);
    hhi[(size_t)r*HID_C+c] = hh;
    hlo[(size_t)r*HID_C+c] = ll;
}

// ---------------- hybrid MFMA GEMM: A via LDS (wave-shared), B direct from L2 ----------------
// r14: r10's full-LDS staging is measured-good but B-staging is pure overhead: each wave
// reads DISJOINT B fragments (nrow depends on wave), so direct global B reads move the
// same total bytes from the same L2-hot 128KB weights — minus the LDS round-trip and 4/5
// of the LDS footprint (51KB -> 10KB). A stays in LDS: all 4 waves read IDENTICAL A
// fragments (direct-A = 4x redundant reads; that was r12's regression).
template<int K, bool PAIR, bool NORM>
__global__ __launch_bounds__(256) void k_mm(const short* __restrict__ Ahi, const short* __restrict__ Alo,
                                            const short* __restrict__ WTl, const float* __restrict__ bl,
                                            const short* __restrict__ WTr, const float* __restrict__ br,
                                            float* __restrict__ XLf, unsigned short* __restrict__ XLh,
                                            unsigned short* __restrict__ XR16){
    constexpr int LDS_K = 40;          // 32 + 8 pad shorts (80B rows)
    constexpr int NCH = K / 32;
    __shared__ short As_hi[64*LDS_K], As_lo[64*LDS_K];
    __shared__ float ssq[NORM?256:1];

    int t = threadIdx.x;
    int lane = t & 63, wave = t >> 6;
    int quad = lane >> 4, ml = lane & 15;
    int rbase = blockIdx.x * 64;

    const short* WTl_lo = WTl + (size_t)K*HC_DIM;
    const short* WTr_lo = PAIR ? (WTr + (size_t)K*HC_DIM) : nullptr;

    f32x4 accL[4][2], accR[4][2];
    #pragma unroll
    for(int i=0;i<4;i++)
        #pragma unroll
        for(int j=0;j<2;j++){ accL[i][j]=(f32x4){0,0,0,0}; accR[i][j]=(f32x4){0,0,0,0}; }

    int r = t >> 2, seg = t & 3;
    int gr = rbase + r; if(gr >= N_NODES) gr = N_NODES-1;

    for(int c=0; c<NCH; c++){
        if(c) __syncthreads();
        size_t ka = (size_t)gr*K + c*32 + seg*8;
        *(short8*)(As_hi + r*LDS_K + seg*8) = *(const short8*)(Ahi + ka);
        *(short8*)(As_lo + r*LDS_K + seg*8) = *(const short8*)(Alo + ka);
        __syncthreads();

        int k0 = quad*8;
        size_t kg = (size_t)(c*32 + quad*8);   // global k offset for B
        short8 ah[4], al[4];
        #pragma unroll
        for(int i=0;i<4;i++){
            ah[i] = *(const short8*)(As_hi + (16*i + ml)*LDS_K + k0);
            al[i] = *(const short8*)(As_lo + (16*i + ml)*LDS_K + k0);
        }
        #pragma unroll
        for(int j=0;j<2;j++){
            int nrow = j*64 + wave*16 + ml;
            short8 bh  = *(const short8*)(WTl    + (size_t)nrow*K + kg);
            short8 blo = *(const short8*)(WTl_lo + (size_t)nrow*K + kg);
            #pragma unroll
            for(int i=0;i<4;i++){
                accL[i][j] = __builtin_amdgcn_mfma_f32_16x16x32_bf16(ah[i], bh,  accL[i][j], 0,0,0);
                accL[i][j] = __builtin_amdgcn_mfma_f32_16x16x32_bf16(ah[i], blo, accL[i][j], 0,0,0);
                accL[i][j] = __builtin_amdgcn_mfma_f32_16x16x32_bf16(al[i], bh,  accL[i][j], 0,0,0);
            }
            if(PAIR){
                short8 ch = *(const short8*)(WTr    + (size_t)nrow*K + kg);
                short8 cl = *(const short8*)(WTr_lo + (size_t)nrow*K + kg);
                #pragma unroll
                for(int i=0;i<4;i++){
                    accR[i][j] = __builtin_amdgcn_mfma_f32_16x16x32_bf16(ah[i], ch, accR[i][j], 0,0,0);
                    accR[i][j] = __builtin_amdgcn_mfma_f32_16x16x32_bf16(ah[i], cl, accR[i][j], 0,0,0);
                    accR[i][j] = __builtin_amdgcn_mfma_f32_16x16x32_bf16(al[i], ch, accR[i][j], 0,0,0);
                }
            }
        }
    }

    int col0 = wave*16 + ml, col1 = 64 + wave*16 + ml;
    float bL0 = bl[col0], bL1 = bl[col1];

    if(NORM){
        #pragma unroll
        for(int i=0;i<4;i++){
            #pragma unroll
            for(int rr=0;rr<4;rr++){
                float v0 = accL[i][0][rr] + bL0;
                float v1 = accL[i][1][rr] + bL1;
                float p = v0*v0 + v1*v1;
                p += __shfl_xor(p,1); p += __shfl_xor(p,2);
                p += __shfl_xor(p,4); p += __shfl_xor(p,8);
                if(ml==0) ssq[wave*64 + 16*i + quad*4 + rr] = p;
            }
        }
        __syncthreads();
        #pragma unroll
        for(int i=0;i<4;i++){
            #pragma unroll
            for(int rr=0;rr<4;rr++){
                int row = 16*i + quad*4 + rr;
                int grr = rbase + row;
                if(grr < N_NODES){
                    float tot = ssq[row] + ssq[64+row] + ssq[128+row] + ssq[192+row];
                    float inv = 1.0f / fmaxf(sqrtf(tot), 1e-12f);
                    XLf[(size_t)grr*HC_DIM + col0] = (accL[i][0][rr] + bL0) * inv;
                    XLf[(size_t)grr*HC_DIM + col1] = (accL[i][1][rr] + bL1) * inv;
                }
            }
        }
    } else {
        float bR0 = PAIR ? br[col0] : 0.f, bR1 = PAIR ? br[col1] : 0.f;
        #pragma unroll
        for(int i=0;i<4;i++){
            #pragma unroll
            for(int rr=0;rr<4;rr++){
                int grr = rbase + 16*i + quad*4 + rr;
                if(grr < N_NODES){
                    XLh[(size_t)grr*HC_DIM + col0] = f2h(accL[i][0][rr] + bL0);
                    XLh[(size_t)grr*HC_DIM + col1] = f2h(accL[i][1][rr] + bL1);
                    if(PAIR){
                        XR16[(size_t)grr*HC_DIM + col0] = f2h(accR[i][0][rr] + bR0);
                        XR16[(size_t)grr*HC_DIM + col1] = f2h(accR[i][1][rr] + bR1);
                    }
                }
            }
        }
    }
}

// ---------------- fused per-node GATv2 (fp16, exact 2 nodes/wave, hoisted constants) ----------------
// r14: r13's grid-stride regressed occupancy (31%): VGPR hit the 64-cliff AND 50000/8192
// = 6.1 nodes/wave left a 17% tail where 848 waves run 7th nodes nearly alone. Fix: 6250
// blocks x 4 waves = 25000 waves, each handling exactly nodes {w, w+25000} — perfect
// balance, constants amortized over 2 nodes, unroll 1 keeps code/VGPR small.
__global__ __launch_bounds__(256) void k_node(const unsigned short* __restrict__ XLH, const unsigned short* __restrict__ XR,
    const int* __restrict__ rowptr, const int* __restrict__ colidx,
    const float* __restrict__ att, const float* __restrict__ bo,
    const float* __restrict__ gg, const float* __restrict__ be,
    const short* __restrict__ hold_hi, const short* __restrict__ hold_lo,
    short* __restrict__ hi_out, short* __restrict__ lo_out)
{
    int wave=threadIdx.x>>6, lane=threadIdx.x&63;
    int qd = lane >> 4, cl = lane & 15;
    int c8 = cl << 3;
    int ch2 = c8 + (qd<<1);   // the 2 channels this lane finalizes

    // ---- hoisted node-invariant constants ----
    float4 aa = *(const float4*)(att + c8);
    float4 abv = *(const float4*)(att + c8 + 4);
    float af[8] = {aa.x,aa.y,aa.z,aa.w,abv.x,abv.y,abv.z,abv.w};
    hf8 av6, av4;
    const float s6 = 0.6f*LOG2E, s4 = 0.4f*LOG2E;
    #pragma unroll
    for(int k=0;k<8;k++){
        av6[k] = (_Float16)(af[k]*s6);
        av4[k] = (_Float16)(af[k]*s4);
    }
    float4 b0 = *(const float4*)(bo + c8);
    float4 b1 = *(const float4*)(bo + c8 + 4);
    float bof[8] = {b0.x,b0.y,b0.z,b0.w,b1.x,b1.y,b1.z,b1.w};
    float2 g2  = *(const float2*)(gg + ch2);
    float2 be2 = *(const float2*)(be + ch2);

    #define H2(v,k) __builtin_shufflevector(v, v, 2*(k), 2*(k)+1)
    #define LOADH(j, xv) { xv = *(const hf8*)((const _Float16*)XR + ((size_t)((unsigned)(j)<<7)) + c8); }
#if defined(__has_builtin) && __has_builtin(__builtin_amdgcn_fdot2)
    // logit: q = sum_head( 0.6*att*log2e * u + 0.4*att*log2e * |u| ), head = 4 lanes -> 2 shfl
    #define LOGIT(xv, q) { \
        hf8 u_ = xlh + xv; \
        hf8 a_ = __builtin_bit_cast(hf8, __builtin_bit_cast(uint4v, u_) & 0x7fff7fffu); \
        float qa_ = __builtin_amdgcn_fdot2(H2(u_,0), H2(av6,0), 0.f, false); \
        float qb_ = __builtin_amdgcn_fdot2(H2(a_,0), H2(av4,0), 0.f, false); \
        qa_ = __builtin_amdgcn_fdot2(H2(u_,1), H2(av6,1), qa_, false); \
        qb_ = __builtin_amdgcn_fdot2(H2(a_,1), H2(av4,1), qb_, false); \
        qa_ = __builtin_amdgcn_fdot2(H2(u_,2), H2(av6,2), qa_, false); \
        qb_ = __builtin_amdgcn_fdot2(H2(a_,2), H2(av4,2), qb_, false); \
        qa_ = __builtin_amdgcn_fdot2(H2(u_,3), H2(av6,3), qa_, false); \
        qb_ = __builtin_amdgcn_fdot2(H2(a_,3), H2(av4,3), qb_, false); \
        q = qa_ + qb_; \
        q += __shfl_xor(q,1); q += __shfl_xor(q,2); }
#else
    #define LOGIT(xv, q) { \
        hf8 u_ = xlh + xv; \
        hf8 a_ = __builtin_bit_cast(hf8, __builtin_bit_cast(uint4v, u_) & 0x7fff7fffu); \
        q = 0.f; \
        _Pragma("unroll") \
        for(int k_=0;k_<8;k_++) q = fmaf((float)u_[k_], (float)av6[k_], fmaf((float)a_[k_], (float)av4[k_], q)); \
        q += __shfl_xor(q,1); q += __shfl_xor(q,2); }
#endif
    #define UPDATE4 { \
        float nm = fmaxf(m, fmaxf(fmaxf(q0,q1),fmaxf(q2,q3))); \
        float sc = exp2f(m-nm); \
        float e0=exp2f(q0-nm), e1=exp2f(q1-nm), e2=exp2f(q2-nm), e3=exp2f(q3-nm); \
        ls = fmaf(ls, sc, (e0+e1)+(e2+e3)); \
        _Pragma("unroll") \
        for(int k=0;k<8;k++) \
            acc[k] = fmaf(acc[k], sc, fmaf(e0,(float)x0[k], fmaf(e1,(float)x1[k], fmaf(e2,(float)x2[k], e3*(float)x3[k])))); \
        m = nm; }

    int nbase = (blockIdx.x<<2) + wave;
    #pragma unroll 1
    for(int rep=0; rep<2; rep++){
        int node = nbase + rep*NODE_HALF;

        // issue independent loads as early as possible
        int beg = rowptr[node], end = rowptr[node+1];
        hf8 xlh = *(const hf8*)((const _Float16*)XLH + ((size_t)((unsigned)node<<7)) + c8);
        hf8 xs; LOADH(node, xs)
        float hres0 = 0.f, hres1 = 0.f;
        if(hold_hi){
            short2 hh = *(const short2*)(hold_hi + (size_t)node*HC_DIM + ch2);
            short2 hl = *(const short2*)(hold_lo + (size_t)node*HC_DIM + ch2);
            hres0 = bf2f((unsigned short)hh.x) + bf2f((unsigned short)hl.x);
            hres1 = bf2f((unsigned short)hh.y) + bf2f((unsigned short)hl.y);
        }

        // self-loop init: only quarter 0 carries it
        float qs; LOGIT(xs, qs)
        float m, ls, acc[8];
        if(qd==0){
            m = qs; ls = 1.f;
            #pragma unroll
            for(int k=0;k<8;k++) acc[k] = (float)xs[k];
        } else {
            m = -1e30f; ls = 0.f;
            #pragma unroll
            for(int k=0;k<8;k++) acc[k] = 0.f;
        }

        int P = end - beg;
        int nb = P >> 4;
        int base = beg;
        int qoff = qd << 2;
        for(int b=0; b<nb; b++, base += 16){
            int b2 = base + qoff;
            int j0 = colidx[b2], j1 = colidx[b2+1], j2 = colidx[b2+2], j3 = colidx[b2+3];
            hf8 x0,x1,x2,x3;
            LOADH(j0,x0) LOADH(j1,x1) LOADH(j2,x2) LOADH(j3,x3)
            float q0,q1,q2,q3;
            LOGIT(x0,q0) LOGIT(x1,q1) LOGIT(x2,q2) LOGIT(x3,q3)
            UPDATE4
        }
        // masked tail: up to 15 remaining edges in ONE batched update per quarter
        if(base < end){
            int b2 = base + qoff;
            int j0 = (b2  <end)? colidx[b2]   : node;
            int j1 = (b2+1<end)? colidx[b2+1] : node;
            int j2 = (b2+2<end)? colidx[b2+2] : node;
            int j3 = (b2+3<end)? colidx[b2+3] : node;
            hf8 x0,x1,x2,x3;
            LOADH(j0,x0) LOADH(j1,x1) LOADH(j2,x2) LOADH(j3,x3)
            float q0,q1,q2,q3;
            LOGIT(x0,q0) LOGIT(x1,q1) LOGIT(x2,q2) LOGIT(x3,q3)
            if(b2+1>=end) q1 = -INFINITY;
            if(b2+2>=end) q2 = -INFINITY;
            if(b2+3>=end) q3 = -INFINITY;
            if(b2 < end){   // quarter has >=1 active slot (q0 finite -> nm finite)
                UPDATE4
            }
        }

        // merge the 4 quarter states: xor 16 then xor 32
        #pragma unroll
        for(int mk=16; mk<=32; mk<<=1){
            float mo  = __shfl_xor(m, mk);
            float lso = __shfl_xor(ls, mk);
            float ao[8];
            #pragma unroll
            for(int k=0;k<8;k++) ao[k] = __shfl_xor(acc[k], mk);
            float nm = fmaxf(m, mo);
            float s0 = exp2f(m-nm), s1 = exp2f(mo-nm);
            ls = ls*s0 + lso*s1;
            #pragma unroll
            for(int k=0;k<8;k++) acc[k] = acc[k]*s0 + ao[k]*s1;
            m = nm;
        }

        float inv = 1.0f/ls;
        float o[8];
        #pragma unroll
        for(int k=0;k<8;k++) o[k] = fmaf(acc[k], inv, bof[k]);
        float s1v = ((o[0]+o[1])+(o[2]+o[3])) + ((o[4]+o[5])+(o[6]+o[7]));
        float s2v = o[0]*o[0];
        #pragma unroll
        for(int k=1;k<8;k++) s2v = fmaf(o[k],o[k],s2v);
        #pragma unroll
        for(int mk=1;mk<16;mk<<=1){ s1v += __shfl_xor(s1v,mk); s2v += __shfl_xor(s2v,mk); }
        float mean = s1v*(1.f/128.f);
        float var  = s2v*(1.f/128.f) - mean*mean;
        float rstd = rsqrtf(var + 1e-5f);

        // each lane finalizes exactly 2 channels: ch2 = 8*cl + 2*qd (covers 0..127)
        float oa = (qd&2) ? ((qd&1)? o[6] : o[4]) : ((qd&1)? o[2] : o[0]);
        float ob = (qd&2) ? ((qd&1)? o[7] : o[5]) : ((qd&1)? o[3] : o[1]);
        float r0 = gelu_f(fmaf(g2.x*(oa-mean), rstd, be2.x)) + hres0;
        float r1 = gelu_f(fmaf(g2.y*(ob-mean), rstd, be2.y)) + hres1;
        short h0,l0,h1,l1;
        split2(r0,h0,l0); split2(r1,h1,l1);
        *(short2*)(hi_out + (size_t)node*HC_DIM + ch2) = make_short2(h0,h1);
        *(short2*)(lo_out + (size_t)node*HC_DIM + ch2) = make_short2(l0,l1);
    }
    #undef UPDATE4
    #undef LOGIT
    #undef LOADH
    #undef H2
}

extern "C" void kernel_launch(void* const* d_in, const int* in_sizes, int n_in,
                              void* d_out, int out_size, void* d_ws, size_t ws_size,
                              hipStream_t stream)
{
    const float* x   = (const float*)d_in[0];
    const int*   ei  = (const int*)  d_in[1];
    const float* Win = (const float*)d_in[2];
    const float* bin = (const float*)d_in[3];
    const float *Wl[3], *bl[3], *Wr[3], *br[3], *att[3], *bo[3], *gg[3], *be[3];
    for(int i=0;i<3;i++){
        const int base = 4 + 8*i;
        Wl[i]=(const float*)d_in[base+0]; bl[i]=(const float*)d_in[base+1];
        Wr[i]=(const float*)d_in[base+2]; br[i]=(const float*)d_in[base+3];
        att[i]=(const float*)d_in[base+4]; bo[i]=(const float*)d_in[base+5];
        gg[i]=(const float*)d_in[base+6]; be[i]=(const float*)d_in[base+7];
    }
    const float* Wout=(const float*)d_in[28];
    const float* bout=(const float*)d_in[29];
    float* out = (float*)d_out;

    char* w = (char*)d_ws;
    unsigned short* XLH = (unsigned short*)w; w += (size_t)N_NODES*HC_DIM*2;
    unsigned short* XR16 = (unsigned short*)w; w += (size_t)N_NODES*HC_DIM*2;
    short* hAhi = (short*)w; w += (size_t)N_NODES*HC_DIM*2;
    short* hAlo = (short*)w; w += (size_t)N_NODES*HC_DIM*2;
    short* hBhi = (short*)w; w += (size_t)N_NODES*HC_DIM*2;
    short* hBlo = (short*)w; w += (size_t)N_NODES*HC_DIM*2;
    short* WT   = (short*)w; w += (size_t)180224*2;
    int* rowptr = (int*)w;  w += (size_t)(N_NODES+2)*4;
    int* cursor = (int*)w;  w += (size_t)N_NODES*4;
    int* colidx = (int*)w;  w += (size_t)N_EDGES*4;
    int* rank   = (int*)w;  w += (size_t)N_EDGES*4;
    int* part   = (int*)w;  w += 256*4;

    const int* srcp = ei;
    const int* dstp = ei + N_EDGES;

    const short* WTl0 = WT + 0;      const short* WTr0 = WT + 8192;
    const short* WTl1 = WT + 16384;  const short* WTr1 = WT + 49152;
    const short* WTl2 = WT + 81920;  const short* WTr2 = WT + 114688;
    const short* WTo  = WT + 147456;

    // ---- weight split + CSR build + input projection ----
    k_splitW<<<22,256,0,stream>>>(Wl[0],Wr[0],Wl[1],Wr[1],Wl[2],Wr[2],Wout, WT);
    hipMemsetAsync(cursor, 0, (size_t)N_NODES*4, stream);
    k_count <<<782,256, 0, stream>>>(dstp, cursor, rank);
    k_scan1 <<<SCAN_NB,256,0,stream>>>(cursor, rowptr, part);
    k_scan2 <<<1,   256, 0, stream>>>(part);
    k_scan3 <<<SCAN_NB,256,0,stream>>>(rowptr, part);
    k_fill  <<<782,256, 0, stream>>>(srcp, dstp, rowptr, rank, colidx);
    k_gemm_in<<<6250,256,0,stream>>>(x, Win, bin, hAhi, hAlo);

    // ---- layer 0: hA[N,32] -> hB (no residual) ----
    k_mm<32,true,false><<<782,256,0,stream>>>(hAhi, hAlo, WTl0, bl[0], WTr0, br[0],
                                              nullptr, XLH, XR16);
    k_node<<<6250,256,0,stream>>>(XLH,XR16,rowptr,colidx,att[0],bo[0],gg[0],be[0],
                                  (const short*)nullptr, (const short*)nullptr, hBhi, hBlo);

    // ---- layer 1: hB -> hA (residual hB) ----
    k_mm<128,true,false><<<782,256,0,stream>>>(hBhi, hBlo, WTl1, bl[1], WTr1, br[1],
                                               nullptr, XLH, XR16);
    k_node<<<6250,256,0,stream>>>(XLH,XR16,rowptr,colidx,att[1],bo[1],gg[1],be[1],
                                  hBhi, hBlo, hAhi, hAlo);

    // ---- layer 2: hA -> hB (residual hA) ----
    k_mm<128,true,false><<<782,256,0,stream>>>(hAhi, hAlo, WTl2, bl[2], WTr2, br[2],
                                               nullptr, XLH, XR16);
    k_node<<<6250,256,0,stream>>>(XLH,XR16,rowptr,colidx,att[2],bo[2],gg[2],be[2],
                                  hAhi, hAlo, hBhi, hBlo);

    // ---- output projection + fused row L2-normalize -> out ----
    k_mm<128,false,true><<<782,256,0,stream>>>(hBhi, hBlo, WTo, bout, nullptr, nullptr,
                                               out, nullptr, nullptr);
}

// Round 9
// 518.295 us; speedup vs baseline: 1.0023x; 1.0023x over previous
//
#include <hip/hip_runtime.h>
#include <hip/hip_bf16.h>
#include <math.h>

#define N_NODES 50000
#define N_EDGES 800000
#define IN_DIM  128
#define HC_DIM  128
#define HID_C   32
#define SCAN_NB 196   // ceil(50000/256)
#define LOG2E   1.4426950408889634f
// k_prep block ranges
#define PREP_SPLITW 22
#define PREP_MEMSET 49
#define PREP_GEMM   6250

typedef __attribute__((ext_vector_type(8))) short short8;   // 8 bf16 = 4 VGPR (MFMA A/B frag)
typedef __attribute__((ext_vector_type(4))) float f32x4;    // MFMA C/D frag
typedef _Float16 hf8 __attribute__((ext_vector_type(8)));
typedef unsigned int uint4v __attribute__((ext_vector_type(4)));

__device__ __forceinline__ float gelu_f(float x){
    return 0.5f*x*(1.0f + erff(x*0.7071067811865475f));
}

// fp32 -> (hi, lo) bf16 split: hi = rn(f), lo = rn(f - hi). hi+lo ~ fp32 (2^-17 rel).
__device__ __forceinline__ void split2(float f, short& h, short& l){
    __hip_bfloat16 bh = __float2bfloat16(f);
    float r = f - __bfloat162float(bh);
    __hip_bfloat16 blo = __float2bfloat16(r);
    h = *reinterpret_cast<short*>(&bh);
    l = *reinterpret_cast<short*>(&blo);
}
__device__ __forceinline__ unsigned short f2h(float f){
    _Float16 h = (_Float16)f;
    return __builtin_bit_cast(unsigned short, h);
}
__device__ __forceinline__ float bf2f(unsigned short u){
    return __uint_as_float(((unsigned)u)<<16);
}

// ---------------- k_prep: splitW (blocks 0..21) + zero cursor/flag (22..70) + gemm_in (71..6320) ----------------
// All three sub-tasks are mutually independent -> one dispatch instead of three.
__global__ __launch_bounds__(256) void k_prep(const float* __restrict__ W0, const float* __restrict__ W1,
                                              const float* __restrict__ W2, const float* __restrict__ W3,
                                              const float* __restrict__ W4, const float* __restrict__ W5,
                                              const float* __restrict__ W6, short* __restrict__ WT,
                                              int* __restrict__ cursor, int* __restrict__ flag,
                                              const float* __restrict__ x, const float* __restrict__ Win,
                                              const float* __restrict__ bin,
                                              short* __restrict__ hhi, short* __restrict__ hlo){
    int bx = blockIdx.x;
    if(bx < PREP_SPLITW){
        // -------- weight split (transposed hi/lo bf16 [n][k]) --------
        int m, kc;
        if(bx < 2){ m = bx; kc = 0; }
        else { m = 2 + (bx-2)/4; kc = (bx-2)&3; }
        const float* src; int K; size_t off;
        switch(m){
            case 0: src=W0; K=32;  off=0;      break;
            case 1: src=W1; K=32;  off=8192;   break;
            case 2: src=W2; K=128; off=16384;  break;
            case 3: src=W3; K=128; off=49152;  break;
            case 4: src=W4; K=128; off=81920;  break;
            case 5: src=W5; K=128; off=114688; break;
            default:src=W6; K=128; off=147456; break;
        }
        short* hi = WT + off;
        short* lo = hi + (size_t)K*HC_DIM;
        #pragma unroll
        for(int i=0;i<16;i++){
            int idx = threadIdx.x + i*256;
            int k = kc*32 + (idx>>7);
            int n = idx & 127;
            float f = src[(size_t)k*HC_DIM + n];
            short h,l; split2(f,h,l);
            hi[(size_t)n*K + k] = h;
            lo[(size_t)n*K + k] = l;
        }
    } else if(bx < PREP_SPLITW + PREP_MEMSET){
        // -------- zero cursor + scan flag --------
        int base = (bx - PREP_SPLITW)*1024 + threadIdx.x;
        #pragma unroll
        for(int i=0;i<4;i++){
            int e = base + i*256;
            if(e < N_NODES) cursor[e] = 0;
        }
        if(bx == PREP_SPLITW && threadIdx.x == 0) *flag = 0;
    } else {
        // -------- input projection: h = gelu(x @ Win + bin), bf16 hi/lo --------
        int id = (bx - PREP_SPLITW - PREP_MEMSET)*256 + threadIdx.x;
        int r = id>>5, c = id&31;
        const float4* x4 = (const float4*)(x + (size_t)r*IN_DIM);
        float acc=0.f;
        #pragma unroll 8
        for(int k=0;k<IN_DIM/4;k++){
            float4 xv = x4[k];
            acc = fmaf(xv.x, Win[(4*k  )*HID_C+c], acc);
            acc = fmaf(xv.y, Win[(4*k+1)*HID_C+c], acc);
            acc = fmaf(xv.z, Win[(4*k+2)*HID_C+c], acc);
            acc = fmaf(xv.w, Win[(4*k+3)*HID_C+c], acc);
        }
        float v = gelu_f(acc + bin[c]);
        short hh,ll; split2(v,hh,ll);
        hhi[(size_t)r*HID_C+c] = hh;
        hlo[(size_t)r*HID_C+c] = ll;
    }
}

// ---------------- CSR build ----------------
__global__ __launch_bounds__(256) void k_count(const int* __restrict__ dst, int* __restrict__ cnt,
                                               int* __restrict__ rank){
    int b = blockIdx.x*1024 + threadIdx.x;
    #pragma unroll
    for(int i=0;i<4;i++){
        int e = b + i*256;
        if(e < N_EDGES) rank[e] = atomicAdd(&cnt[dst[e]], 1);
    }
}

// scan1 + last-block-does-scan2 (threadFenceReduction pattern).
__global__ __launch_bounds__(256) void k_scan12(const int* __restrict__ cnt, int* __restrict__ rowptr,
                                                int* __restrict__ part, int* __restrict__ flag){
    __shared__ int sh[256];
    __shared__ int amLast;
    int t=threadIdx.x; int i=blockIdx.x*256+t;
    int v = (i<N_NODES)? cnt[i] : 0;
    sh[t]=v; __syncthreads();
    for(int off=1; off<256; off<<=1){
        int y = (t>=off)? sh[t-off] : 0;
        __syncthreads();
        sh[t] += y;
        __syncthreads();
    }
    if(i<N_NODES) rowptr[i] = sh[t]-v;
    if(t==255) part[blockIdx.x] = sh[255];

    __threadfence();              // make part[] write visible device-wide
    if(t==0){
        int old = atomicAdd(flag, 1);
        amLast = (old == (int)gridDim.x - 1);
    }
    __syncthreads();
    if(amLast){
        __threadfence();          // acquire: see all other blocks' part[] writes
        volatile int* vp = part;
        int v2 = (t<SCAN_NB)? vp[t] : 0;
        sh[t]=v2; __syncthreads();
        for(int off=1; off<256; off<<=1){
            int y=(t>=off)? sh[t-off]:0;
            __syncthreads();
            sh[t]+=y;
            __syncthreads();
        }
        if(t<SCAN_NB) part[t] = sh[t]-v2;
    }
}

// fill + scan3 fused: colidx offset computed as rowptr(partial) + part + rank (rowptr only READ
// -> no race); blocks 0..195 additionally emit finalized rowfin[] for k_node.
__global__ __launch_bounds__(256) void k_fill(const int* __restrict__ src, const int* __restrict__ dst,
                                              const int* __restrict__ rowptr, const int* __restrict__ part,
                                              const int* __restrict__ rank, int* __restrict__ col,
                                              int* __restrict__ rowfin){
    int b = blockIdx.x*1024 + threadIdx.x;
    #pragma unroll
    for(int i=0;i<4;i++){
        int e = b + i*256;
        if(e < N_EDGES){
            int d = dst[e];
            col[rowptr[d] + part[d>>8] + rank[e]] = src[e];
        }
    }
    if(blockIdx.x < SCAN_NB){
        int i = blockIdx.x*256 + threadIdx.x;
        if(i < N_NODES) rowfin[i] = rowptr[i] + part[i>>8];
        if(i == 0) rowfin[N_NODES] = N_EDGES;
    }
}

// ---------------- full-width MFMA GEMM, LDS-staged (bf16x3, ~fp32) ----------------
// r13 version (best-measured ensemble). fp16 XL/XR outputs; NORM fuses bias + L2-normalize.
template<int K, bool PAIR, bool NORM>
__global__ __launch_bounds__(256) void k_mm(const short* __restrict__ Ahi, const short* __restrict__ Alo,
                                            const short* __restrict__ WTl, const float* __restrict__ bl,
                                            const short* __restrict__ WTr, const float* __restrict__ br,
                                            float* __restrict__ XLf, unsigned short* __restrict__ XLh,
                                            unsigned short* __restrict__ XR16){
    constexpr int LDS_K = 40;          // 32 + 8 pad shorts (80B rows)
    constexpr int NCH = K / 32;
    __shared__ short As_hi[64*LDS_K], As_lo[64*LDS_K];
    __shared__ short Bh0[128*LDS_K], Bl0[128*LDS_K];
    __shared__ short Bh1[PAIR?128*LDS_K:1], Bl1[PAIR?128*LDS_K:1];
    __shared__ float ssq[NORM?256:1];

    int t = threadIdx.x;
    int lane = t & 63, wave = t >> 6;
    int quad = lane >> 4, ml = lane & 15;
    int rbase = blockIdx.x * 64;

    const short* WTl_lo = WTl + (size_t)K*HC_DIM;
    const short* WTr_lo = PAIR ? (WTr + (size_t)K*HC_DIM) : nullptr;

    f32x4 accL[4][2], accR[4][2];
    #pragma unroll
    for(int i=0;i<4;i++)
        #pragma unroll
        for(int j=0;j<2;j++){ accL[i][j]=(f32x4){0,0,0,0}; accR[i][j]=(f32x4){0,0,0,0}; }

    int r = t >> 2, seg = t & 3;
    int gr = rbase + r; if(gr >= N_NODES) gr = N_NODES-1;

    for(int c=0; c<NCH; c++){
        if(c) __syncthreads();
        size_t ka = (size_t)gr*K + c*32 + seg*8;
        *(short8*)(As_hi + r*LDS_K + seg*8) = *(const short8*)(Ahi + ka);
        *(short8*)(As_lo + r*LDS_K + seg*8) = *(const short8*)(Alo + ka);
        #pragma unroll
        for(int u=0; u<2; u++){
            int uu = t + u*256;
            int n = uu >> 2, sg = uu & 3;
            size_t kw = (size_t)n*K + c*32 + sg*8;
            *(short8*)(Bh0 + n*LDS_K + sg*8) = *(const short8*)(WTl + kw);
            *(short8*)(Bl0 + n*LDS_K + sg*8) = *(const short8*)(WTl_lo + kw);
            if(PAIR){
                *(short8*)(Bh1 + n*LDS_K + sg*8) = *(const short8*)(WTr + kw);
                *(short8*)(Bl1 + n*LDS_K + sg*8) = *(const short8*)(WTr_lo + kw);
            }
        }
        __syncthreads();

        int k0 = quad*8;
        short8 ah[4], al[4];
        #pragma unroll
        for(int i=0;i<4;i++){
            ah[i] = *(const short8*)(As_hi + (16*i + ml)*LDS_K + k0);
            al[i] = *(const short8*)(As_lo + (16*i + ml)*LDS_K + k0);
        }
        #pragma unroll
        for(int j=0;j<2;j++){
            int nrow = j*64 + wave*16 + ml;
            short8 bh = *(const short8*)(Bh0 + nrow*LDS_K + k0);
            short8 blo = *(const short8*)(Bl0 + nrow*LDS_K + k0);
            #pragma unroll
            for(int i=0;i<4;i++){
                accL[i][j] = __builtin_amdgcn_mfma_f32_16x16x32_bf16(ah[i], bh,  accL[i][j], 0,0,0);
                accL[i][j] = __builtin_amdgcn_mfma_f32_16x16x32_bf16(ah[i], blo, accL[i][j], 0,0,0);
                accL[i][j] = __builtin_amdgcn_mfma_f32_16x16x32_bf16(al[i], bh,  accL[i][j], 0,0,0);
            }
            if(PAIR){
                short8 ch = *(const short8*)(Bh1 + nrow*LDS_K + k0);
                short8 cl = *(const short8*)(Bl1 + nrow*LDS_K + k0);
                #pragma unroll
                for(int i=0;i<4;i++){
                    accR[i][j] = __builtin_amdgcn_mfma_f32_16x16x32_bf16(ah[i], ch, accR[i][j], 0,0,0);
                    accR[i][j] = __builtin_amdgcn_mfma_f32_16x16x32_bf16(ah[i], cl, accR[i][j], 0,0,0);
                    accR[i][j] = __builtin_amdgcn_mfma_f32_16x16x32_bf16(al[i], ch, accR[i][j], 0,0,0);
                }
            }
        }
    }

    int col0 = wave*16 + ml, col1 = 64 + wave*16 + ml;
    float bL0 = bl[col0], bL1 = bl[col1];

    if(NORM){
        #pragma unroll
        for(int i=0;i<4;i++){
            #pragma unroll
            for(int rr=0;rr<4;rr++){
                float v0 = accL[i][0][rr] + bL0;
                float v1 = accL[i][1][rr] + bL1;
                float p = v0*v0 + v1*v1;
                p += __shfl_xor(p,1); p += __shfl_xor(p,2);
                p += __shfl_xor(p,4); p += __shfl_xor(p,8);
                if(ml==0) ssq[wave*64 + 16*i + quad*4 + rr] = p;
            }
        }
        __syncthreads();
        #pragma unroll
        for(int i=0;i<4;i++){
            #pragma unroll
            for(int rr=0;rr<4;rr++){
                int row = 16*i + quad*4 + rr;
                int grr = rbase + row;
                if(grr < N_NODES){
                    float tot = ssq[row] + ssq[64+row] + ssq[128+row] + ssq[192+row];
                    float inv = 1.0f / fmaxf(sqrtf(tot), 1e-12f);
                    XLf[(size_t)grr*HC_DIM + col0] = (accL[i][0][rr] + bL0) * inv;
                    XLf[(size_t)grr*HC_DIM + col1] = (accL[i][1][rr] + bL1) * inv;
                }
            }
        }
    } else {
        float bR0 = PAIR ? br[col0] : 0.f, bR1 = PAIR ? br[col1] : 0.f;
        #pragma unroll
        for(int i=0;i<4;i++){
            #pragma unroll
            for(int rr=0;rr<4;rr++){
                int grr = rbase + 16*i + quad*4 + rr;
                if(grr < N_NODES){
                    XLh[(size_t)grr*HC_DIM + col0] = f2h(accL[i][0][rr] + bL0);
                    XLh[(size_t)grr*HC_DIM + col1] = f2h(accL[i][1][rr] + bL1);
                    if(PAIR){
                        XR16[(size_t)grr*HC_DIM + col0] = f2h(accR[i][0][rr] + bR0);
                        XR16[(size_t)grr*HC_DIM + col1] = f2h(accR[i][1][rr] + bR1);
                    }
                }
            }
        }
    }
}

// ---------------- fused per-node GATv2 (fp16, 1 node/wave, hoisted constants) ----------------
// r15: k_node plateaued 68-71us across 5 shapes; best occupancy (51%) was r10's
// 12500-block 1-node/wave dispatch. Take that shape with the r14 lean body.
__global__ __launch_bounds__(256) void k_node(const unsigned short* __restrict__ XLH, const unsigned short* __restrict__ XR,
    const int* __restrict__ rowptr, const int* __restrict__ colidx,
    const float* __restrict__ att, const float* __restrict__ bo,
    const float* __restrict__ gg, const float* __restrict__ be,
    const short* __restrict__ hold_hi, const short* __restrict__ hold_lo,
    short* __restrict__ hi_out, short* __restrict__ lo_out)
{
    int wave=threadIdx.x>>6, lane=threadIdx.x&63;
    int node = blockIdx.x*4 + wave;
    int qd = lane >> 4, cl = lane & 15;
    int c8 = cl << 3;
    int ch2 = c8 + (qd<<1);   // the 2 channels this lane finalizes

    // ---- constants ----
    float4 aa = *(const float4*)(att + c8);
    float4 abv = *(const float4*)(att + c8 + 4);
    float af[8] = {aa.x,aa.y,aa.z,aa.w,abv.x,abv.y,abv.z,abv.w};
    hf8 av6, av4;
    const float s6 = 0.6f*LOG2E, s4 = 0.4f*LOG2E;
    #pragma unroll
    for(int k=0;k<8;k++){
        av6[k] = (_Float16)(af[k]*s6);
        av4[k] = (_Float16)(af[k]*s4);
    }
    float4 b0 = *(const float4*)(bo + c8);
    float4 b1 = *(const float4*)(bo + c8 + 4);
    float bof[8] = {b0.x,b0.y,b0.z,b0.w,b1.x,b1.y,b1.z,b1.w};
    float2 g2  = *(const float2*)(gg + ch2);
    float2 be2 = *(const float2*)(be + ch2);

    #define H2(v,k) __builtin_shufflevector(v, v, 2*(k), 2*(k)+1)
    #define LOADH(j, xv) { xv = *(const hf8*)((const _Float16*)XR + ((size_t)((unsigned)(j)<<7)) + c8); }
#if defined(__has_builtin) && __has_builtin(__builtin_amdgcn_fdot2)
    // logit: q = sum_head( 0.6*att*log2e * u + 0.4*att*log2e * |u| ), head = 4 lanes -> 2 shfl
    #define LOGIT(xv, q) { \
        hf8 u_ = xlh + xv; \
        hf8 a_ = __builtin_bit_cast(hf8, __builtin_bit_cast(uint4v, u_) & 0x7fff7fffu); \
        float qa_ = __builtin_amdgcn_fdot2(H2(u_,0), H2(av6,0), 0.f, false); \
        float qb_ = __builtin_amdgcn_fdot2(H2(a_,0), H2(av4,0), 0.f, false); \
        qa_ = __builtin_amdgcn_fdot2(H2(u_,1), H2(av6,1), qa_, false); \
        qb_ = __builtin_amdgcn_fdot2(H2(a_,1), H2(av4,1), qb_, false); \
        qa_ = __builtin_amdgcn_fdot2(H2(u_,2), H2(av6,2), qa_, false); \
        qb_ = __builtin_amdgcn_fdot2(H2(a_,2), H2(av4,2), qb_, false); \
        qa_ = __builtin_amdgcn_fdot2(H2(u_,3), H2(av6,3), qa_, false); \
        qb_ = __builtin_amdgcn_fdot2(H2(a_,3), H2(av4,3), qb_, false); \
        q = qa_ + qb_; \
        q += __shfl_xor(q,1); q += __shfl_xor(q,2); }
#else
    #define LOGIT(xv, q) { \
        hf8 u_ = xlh + xv; \
        hf8 a_ = __builtin_bit_cast(hf8, __builtin_bit_cast(uint4v, u_) & 0x7fff7fffu); \
        q = 0.f; \
        _Pragma("unroll") \
        for(int k_=0;k_<8;k_++) q = fmaf((float)u_[k_], (float)av6[k_], fmaf((float)a_[k_], (float)av4[k_], q)); \
        q += __shfl_xor(q,1); q += __shfl_xor(q,2); }
#endif
    #define UPDATE4 { \
        float nm = fmaxf(m, fmaxf(fmaxf(q0,q1),fmaxf(q2,q3))); \
        float sc = exp2f(m-nm); \
        float e0=exp2f(q0-nm), e1=exp2f(q1-nm), e2=exp2f(q2-nm), e3=exp2f(q3-nm); \
        ls = fmaf(ls, sc, (e0+e1)+(e2+e3)); \
        _Pragma("unroll") \
        for(int k=0;k<8;k++) \
            acc[k] = fmaf(acc[k], sc, fmaf(e0,(float)x0[k], fmaf(e1,(float)x1[k], fmaf(e2,(float)x2[k], e3*(float)x3[k])))); \
        m = nm; }

    // issue independent loads as early as possible
    int beg = rowptr[node], end = rowptr[node+1];
    hf8 xlh = *(const hf8*)((const _Float16*)XLH + ((size_t)((unsigned)node<<7)) + c8);
    hf8 xs; LOADH(node, xs)
    float hres0 = 0.f, hres1 = 0.f;
    if(hold_hi){
        short2 hh = *(const short2*)(hold_hi + (size_t)node*HC_DIM + ch2);
        short2 hl = *(const short2*)(hold_lo + (size_t)node*HC_DIM + ch2);
        hres0 = bf2f((unsigned short)hh.x) + bf2f((unsigned short)hl.x);
        hres1 = bf2f((unsigned short)hh.y) + bf2f((unsigned short)hl.y);
    }

    // self-loop init: only quarter 0 carries it
    float qs; LOGIT(xs, qs)
    float m, ls, acc[8];
    if(qd==0){
        m = qs; ls = 1.f;
        #pragma unroll
        for(int k=0;k<8;k++) acc[k] = (float)xs[k];
    } else {
        m = -1e30f; ls = 0.f;
        #pragma unroll
        for(int k=0;k<8;k++) acc[k] = 0.f;
    }

    int P = end - beg;
    int nb = P >> 4;
    int base = beg;
    int qoff = qd << 2;
    for(int b=0; b<nb; b++, base += 16){
        int b2 = base + qoff;
        int j0 = colidx[b2], j1 = colidx[b2+1], j2 = colidx[b2+2], j3 = colidx[b2+3];
        hf8 x0,x1,x2,x3;
        LOADH(j0,x0) LOADH(j1,x1) LOADH(j2,x2) LOADH(j3,x3)
        float q0,q1,q2,q3;
        LOGIT(x0,q0) LOGIT(x1,q1) LOGIT(x2,q2) LOGIT(x3,q3)
        UPDATE4
    }
    // masked tail: up to 15 remaining edges in ONE batched update per quarter
    if(base < end){
        int b2 = base + qoff;
        int j0 = (b2  <end)? colidx[b2]   : node;
        int j1 = (b2+1<end)? colidx[b2+1] : node;
        int j2 = (b2+2<end)? colidx[b2+2] : node;
        int j3 = (b2+3<end)? colidx[b2+3] : node;
        hf8 x0,x1,x2,x3;
        LOADH(j0,x0) LOADH(j1,x1) LOADH(j2,x2) LOADH(j3,x3)
        float q0,q1,q2,q3;
        LOGIT(x0,q0) LOGIT(x1,q1) LOGIT(x2,q2) LOGIT(x3,q3)
        if(b2+1>=end) q1 = -INFINITY;
        if(b2+2>=end) q2 = -INFINITY;
        if(b2+3>=end) q3 = -INFINITY;
        if(b2 < end){   // quarter has >=1 active slot (q0 finite -> nm finite)
            UPDATE4
        }
    }
    #undef UPDATE4
    #undef LOGIT
    #undef LOADH
    #undef H2

    // merge the 4 quarter states: xor 16 then xor 32
    #pragma unroll
    for(int mk=16; mk<=32; mk<<=1){
        float mo  = __shfl_xor(m, mk);
        float lso = __shfl_xor(ls, mk);
        float ao[8];
        #pragma unroll
        for(int k=0;k<8;k++) ao[k] = __shfl_xor(acc[k], mk);
        float nm = fmaxf(m, mo);
        float s0 = exp2f(m-nm), s1 = exp2f(mo-nm);
        ls = ls*s0 + lso*s1;
        #pragma unroll
        for(int k=0;k<8;k++) acc[k] = acc[k]*s0 + ao[k]*s1;
        m = nm;
    }

    float inv = 1.0f/ls;
    float o[8];
    #pragma unroll
    for(int k=0;k<8;k++) o[k] = fmaf(acc[k], inv, bof[k]);
    float s1v = ((o[0]+o[1])+(o[2]+o[3])) + ((o[4]+o[5])+(o[6]+o[7]));
    float s2v = o[0]*o[0];
    #pragma unroll
    for(int k=1;k<8;k++) s2v = fmaf(o[k],o[k],s2v);
    #pragma unroll
    for(int mk=1;mk<16;mk<<=1){ s1v += __shfl_xor(s1v,mk); s2v += __shfl_xor(s2v,mk); }
    float mean = s1v*(1.f/128.f);
    float var  = s2v*(1.f/128.f) - mean*mean;
    float rstd = rsqrtf(var + 1e-5f);

    // each lane finalizes exactly 2 channels: ch2 = 8*cl + 2*qd (covers 0..127)
    float oa = (qd&2) ? ((qd&1)? o[6] : o[4]) : ((qd&1)? o[2] : o[0]);
    float ob = (qd&2) ? ((qd&1)? o[7] : o[5]) : ((qd&1)? o[3] : o[1]);
    float r0 = gelu_f(fmaf(g2.x*(oa-mean), rstd, be2.x)) + hres0;
    float r1 = gelu_f(fmaf(g2.y*(ob-mean), rstd, be2.y)) + hres1;
    short h0,l0,h1,l1;
    split2(r0,h0,l0); split2(r1,h1,l1);
    *(short2*)(hi_out + (size_t)node*HC_DIM + ch2) = make_short2(h0,h1);
    *(short2*)(lo_out + (size_t)node*HC_DIM + ch2) = make_short2(l0,l1);
}

extern "C" void kernel_launch(void* const* d_in, const int* in_sizes, int n_in,
                              void* d_out, int out_size, void* d_ws, size_t ws_size,
                              hipStream_t stream)
{
    const float* x   = (const float*)d_in[0];
    const int*   ei  = (const int*)  d_in[1];
    const float* Win = (const float*)d_in[2];
    const float* bin = (const float*)d_in[3];
    const float *Wl[3], *bl[3], *Wr[3], *br[3], *att[3], *bo[3], *gg[3], *be[3];
    for(int i=0;i<3;i++){
        const int base = 4 + 8*i;
        Wl[i]=(const float*)d_in[base+0]; bl[i]=(const float*)d_in[base+1];
        Wr[i]=(const float*)d_in[base+2]; br[i]=(const float*)d_in[base+3];
        att[i]=(const float*)d_in[base+4]; bo[i]=(const float*)d_in[base+5];
        gg[i]=(const float*)d_in[base+6]; be[i]=(const float*)d_in[base+7];
    }
    const float* Wout=(const float*)d_in[28];
    const float* bout=(const float*)d_in[29];
    float* out = (float*)d_out;

    char* w = (char*)d_ws;
    unsigned short* XLH = (unsigned short*)w; w += (size_t)N_NODES*HC_DIM*2;
    unsigned short* XR16 = (unsigned short*)w; w += (size_t)N_NODES*HC_DIM*2;
    short* hAhi = (short*)w; w += (size_t)N_NODES*HC_DIM*2;
    short* hAlo = (short*)w; w += (size_t)N_NODES*HC_DIM*2;
    short* hBhi = (short*)w; w += (size_t)N_NODES*HC_DIM*2;
    short* hBlo = (short*)w; w += (size_t)N_NODES*HC_DIM*2;
    short* WT   = (short*)w; w += (size_t)180224*2;
    int* rowptr = (int*)w;  w += (size_t)(N_NODES+2)*4;
    int* rowfin = (int*)w;  w += (size_t)(N_NODES+2)*4;
    int* cursor = (int*)w;  w += (size_t)N_NODES*4;
    int* colidx = (int*)w;  w += (size_t)N_EDGES*4;
    int* rank   = (int*)w;  w += (size_t)N_EDGES*4;
    int* part   = (int*)w;  w += 256*4;
    int* flag   = (int*)w;  w += 64;

    const int* srcp = ei;
    const int* dstp = ei + N_EDGES;

    const short* WTl0 = WT + 0;      const short* WTr0 = WT + 8192;
    const short* WTl1 = WT + 16384;  const short* WTr1 = WT + 49152;
    const short* WTl2 = WT + 81920;  const short* WTr2 = WT + 114688;
    const short* WTo  = WT + 147456;

    // ---- prep (splitW + zero + input projection) + CSR build ----
    k_prep  <<<PREP_SPLITW+PREP_MEMSET+PREP_GEMM,256,0,stream>>>(
              Wl[0],Wr[0],Wl[1],Wr[1],Wl[2],Wr[2],Wout, WT, cursor, flag,
              x, Win, bin, hAhi, hAlo);
    k_count <<<782,256, 0, stream>>>(dstp, cursor, rank);
    k_scan12<<<SCAN_NB,256,0,stream>>>(cursor, rowptr, part, flag);
    k_fill  <<<782,256, 0, stream>>>(srcp, dstp, rowptr, part, rank, colidx, rowfin);

    // ---- layer 0: hA[N,32] -> hB (no residual) ----
    k_mm<32,true,false><<<782,256,0,stream>>>(hAhi, hAlo, WTl0, bl[0], WTr0, br[0],
                                              nullptr, XLH, XR16);
    k_node<<<12500,256,0,stream>>>(XLH,XR16,rowfin,colidx,att[0],bo[0],gg[0],be[0],
                                   (const short*)nullptr, (const short*)nullptr, hBhi, hBlo);

    // ---- layer 1: hB -> hA (residual hB) ----
    k_mm<128,true,false><<<782,256,0,stream>>>(hBhi, hBlo, WTl1, bl[1], WTr1, br[1],
                                               nullptr, XLH, XR16);
    k_node<<<12500,256,0,stream>>>(XLH,XR16,rowfin,colidx,att[1],bo[1],gg[1],be[1],
                                   hBhi, hBlo, hAhi, hAlo);

    // ---- layer 2: hA -> hB (residual hA) ----
    k_mm<128,true,false><<<782,256,0,stream>>>(hAhi, hAlo, WTl2, bl[2], WTr2, br[2],
                                               nullptr, XLH, XR16);
    k_node<<<12500,256,0,stream>>>(XLH,XR16,rowfin,colidx,att[2],bo[2],gg[2],be[2],
                                   hAhi, hAlo, hBhi, hBlo);

    // ---- output projection + fused row L2-normalize -> out ----
    k_mm<128,false,true><<<782,256,0,stream>>>(hBhi, hBlo, WTo, bout, nullptr, nullptr,
                                               out, nullptr, nullptr);
}

// Round 10
// 500.142 us; speedup vs baseline: 1.0387x; 1.0363x over previous
//
#include <hip/hip_runtime.h>
#include <hip/hip_bf16.h>
#include <math.h>

#define N_NODES 50000
#define N_EDGES 800000
#define IN_DIM  128
#define HC_DIM  128
#define HID_C   32
#define SCAN_NB 196   // ceil(50000/256)
#define LOG2E   1.4426950408889634f
// k_prep block ranges
#define PREP_SPLITW 22
#define PREP_MEMSET 49
#define PREP_GEMM   6250

typedef __attribute__((ext_vector_type(8))) short short8;   // 8 bf16 = 4 VGPR (MFMA A/B frag)
typedef __attribute__((ext_vector_type(4))) short short4v;
typedef __attribute__((ext_vector_type(4))) float f32x4;    // MFMA C/D frag
typedef _Float16 hf8 __attribute__((ext_vector_type(8)));
typedef unsigned int uint4v __attribute__((ext_vector_type(4)));

__device__ __forceinline__ float gelu_f(float x){
    return 0.5f*x*(1.0f + erff(x*0.7071067811865475f));
}

// fp32 -> (hi, lo) bf16 split: hi = rn(f), lo = rn(f - hi).
__device__ __forceinline__ void split2(float f, short& h, short& l){
    __hip_bfloat16 bh = __float2bfloat16(f);
    float r = f - __bfloat162float(bh);
    __hip_bfloat16 blo = __float2bfloat16(r);
    h = *reinterpret_cast<short*>(&bh);
    l = *reinterpret_cast<short*>(&blo);
}
__device__ __forceinline__ unsigned short f2h(float f){
    _Float16 h = (_Float16)f;
    return __builtin_bit_cast(unsigned short, h);
}

// ---------------- k_prep: splitW (0..21) + zero cursor/flag (22..70) + gemm_in (71..6320) ----------------
__global__ __launch_bounds__(256) void k_prep(const float* __restrict__ W0, const float* __restrict__ W1,
                                              const float* __restrict__ W2, const float* __restrict__ W3,
                                              const float* __restrict__ W4, const float* __restrict__ W5,
                                              const float* __restrict__ W6, short* __restrict__ WT,
                                              int* __restrict__ cursor, int* __restrict__ flag,
                                              const float* __restrict__ x, const float* __restrict__ Win,
                                              const float* __restrict__ bin, float* __restrict__ h,
                                              short* __restrict__ hhi, short* __restrict__ hlo){
    int bx = blockIdx.x;
    if(bx < PREP_SPLITW){
        int m, kc;
        if(bx < 2){ m = bx; kc = 0; }
        else { m = 2 + (bx-2)/4; kc = (bx-2)&3; }
        const float* src; int K; size_t off;
        switch(m){
            case 0: src=W0; K=32;  off=0;      break;
            case 1: src=W1; K=32;  off=8192;   break;
            case 2: src=W2; K=128; off=16384;  break;
            case 3: src=W3; K=128; off=49152;  break;
            case 4: src=W4; K=128; off=81920;  break;
            case 5: src=W5; K=128; off=114688; break;
            default:src=W6; K=128; off=147456; break;
        }
        short* hi = WT + off;
        short* lo = hi + (size_t)K*HC_DIM;
        #pragma unroll
        for(int i=0;i<16;i++){
            int idx = threadIdx.x + i*256;
            int k = kc*32 + (idx>>7);
            int n = idx & 127;
            float f = src[(size_t)k*HC_DIM + n];
            short hh,ll; split2(f,hh,ll);
            hi[(size_t)n*K + k] = hh;
            lo[(size_t)n*K + k] = ll;
        }
    } else if(bx < PREP_SPLITW + PREP_MEMSET){
        int base = (bx - PREP_SPLITW)*1024 + threadIdx.x;
        #pragma unroll
        for(int i=0;i<4;i++){
            int e = base + i*256;
            if(e < N_NODES) cursor[e] = 0;
        }
        if(bx == PREP_SPLITW && threadIdx.x == 0) *flag = 0;
    } else {
        int id = (bx - PREP_SPLITW - PREP_MEMSET)*256 + threadIdx.x;
        int r = id>>5, c = id&31;
        const float4* x4 = (const float4*)(x + (size_t)r*IN_DIM);
        float acc=0.f;
        #pragma unroll 8
        for(int k=0;k<IN_DIM/4;k++){
            float4 xv = x4[k];
            acc = fmaf(xv.x, Win[(4*k  )*HID_C+c], acc);
            acc = fmaf(xv.y, Win[(4*k+1)*HID_C+c], acc);
            acc = fmaf(xv.z, Win[(4*k+2)*HID_C+c], acc);
            acc = fmaf(xv.w, Win[(4*k+3)*HID_C+c], acc);
        }
        float v = gelu_f(acc + bin[c]);
        h[(size_t)r*HID_C+c] = v;
        short hh,ll; split2(v,hh,ll);
        hhi[(size_t)r*HID_C+c] = hh;
        hlo[(size_t)r*HID_C+c] = ll;
    }
}

// ---------------- CSR build ----------------
__global__ __launch_bounds__(256) void k_count(const int* __restrict__ dst, int* __restrict__ cnt,
                                               int* __restrict__ rank){
    int b = blockIdx.x*1024 + threadIdx.x;
    #pragma unroll
    for(int i=0;i<4;i++){
        int e = b + i*256;
        if(e < N_EDGES) rank[e] = atomicAdd(&cnt[dst[e]], 1);
    }
}

// scan1 + last-block-does-scan2 (threadFenceReduction pattern).
__global__ __launch_bounds__(256) void k_scan12(const int* __restrict__ cnt, int* __restrict__ rowptr,
                                                int* __restrict__ part, int* __restrict__ flag){
    __shared__ int sh[256];
    __shared__ int amLast;
    int t=threadIdx.x; int i=blockIdx.x*256+t;
    int v = (i<N_NODES)? cnt[i] : 0;
    sh[t]=v; __syncthreads();
    for(int off=1; off<256; off<<=1){
        int y = (t>=off)? sh[t-off] : 0;
        __syncthreads();
        sh[t] += y;
        __syncthreads();
    }
    if(i<N_NODES) rowptr[i] = sh[t]-v;
    if(t==255) part[blockIdx.x] = sh[255];

    __threadfence();
    if(t==0){
        int old = atomicAdd(flag, 1);
        amLast = (old == (int)gridDim.x - 1);
    }
    __syncthreads();
    if(amLast){
        __threadfence();
        volatile int* vp = part;
        int v2 = (t<SCAN_NB)? vp[t] : 0;
        sh[t]=v2; __syncthreads();
        for(int off=1; off<256; off<<=1){
            int y=(t>=off)? sh[t-off]:0;
            __syncthreads();
            sh[t]+=y;
            __syncthreads();
        }
        if(t<SCAN_NB) part[t] = sh[t]-v2;
    }
}

// fill + scan3 fused; blocks 0..195 emit finalized rowfin[].
__global__ __launch_bounds__(256) void k_fill(const int* __restrict__ src, const int* __restrict__ dst,
                                              const int* __restrict__ rowptr, const int* __restrict__ part,
                                              const int* __restrict__ rank, int* __restrict__ col,
                                              int* __restrict__ rowfin){
    int b = blockIdx.x*1024 + threadIdx.x;
    #pragma unroll
    for(int i=0;i<4;i++){
        int e = b + i*256;
        if(e < N_EDGES){
            int d = dst[e];
            col[rowptr[d] + part[d>>8] + rank[e]] = src[e];
        }
    }
    if(blockIdx.x < SCAN_NB){
        int i = blockIdx.x*256 + threadIdx.x;
        if(i < N_NODES) rowfin[i] = rowptr[i] + part[i>>8];
        if(i == 0) rowfin[N_NODES] = N_EDGES;
    }
}

// ---------------- full-width MFMA GEMM (bf16x3, ~fp32) — round-2-verified version ----------------
// XL out f32, XR out fp16. NORM fuses bias + row-L2-normalize -> final f32 out.
template<int K, bool PAIR, bool NORM>
__global__ __launch_bounds__(256) void k_mfma(const short* __restrict__ Ahi, const short* __restrict__ Alo,
                                              const short* __restrict__ WTl, const float* __restrict__ bl,
                                              const short* __restrict__ WTr, const float* __restrict__ br,
                                              float* __restrict__ XL, unsigned short* __restrict__ XR16){
    constexpr int LDS_K = 40;          // 32 + 8 pad shorts (80B rows)
    constexpr int NCH = K / 32;
    __shared__ short As_hi[64*LDS_K], As_lo[64*LDS_K];
    __shared__ short Bh0[128*LDS_K], Bl0[128*LDS_K];
    __shared__ short Bh1[PAIR?128*LDS_K:1], Bl1[PAIR?128*LDS_K:1];
    __shared__ float ssq[NORM?256:1];

    int t = threadIdx.x;
    int lane = t & 63, wave = t >> 6;
    int quad = lane >> 4, ml = lane & 15;
    int rbase = blockIdx.x * 64;

    const short* WTl_lo = WTl + (size_t)K*HC_DIM;
    const short* WTr_lo = PAIR ? (WTr + (size_t)K*HC_DIM) : nullptr;

    f32x4 accL[4][2], accR[4][2];
    #pragma unroll
    for(int i=0;i<4;i++)
        #pragma unroll
        for(int j=0;j<2;j++){ accL[i][j]=(f32x4){0,0,0,0}; accR[i][j]=(f32x4){0,0,0,0}; }

    int r = t >> 2, seg = t & 3;
    int gr = rbase + r; if(gr >= N_NODES) gr = N_NODES-1;

    for(int c=0; c<NCH; c++){
        if(c) __syncthreads();
        size_t ka = (size_t)gr*K + c*32 + seg*8;
        *(short8*)(As_hi + r*LDS_K + seg*8) = *(const short8*)(Ahi + ka);
        *(short8*)(As_lo + r*LDS_K + seg*8) = *(const short8*)(Alo + ka);
        #pragma unroll
        for(int u=0; u<2; u++){
            int uu = t + u*256;
            int n = uu >> 2, sg = uu & 3;
            size_t kw = (size_t)n*K + c*32 + sg*8;
            *(short8*)(Bh0 + n*LDS_K + sg*8) = *(const short8*)(WTl + kw);
            *(short8*)(Bl0 + n*LDS_K + sg*8) = *(const short8*)(WTl_lo + kw);
            if(PAIR){
                *(short8*)(Bh1 + n*LDS_K + sg*8) = *(const short8*)(WTr + kw);
                *(short8*)(Bl1 + n*LDS_K + sg*8) = *(const short8*)(WTr_lo + kw);
            }
        }
        __syncthreads();

        int k0 = quad*8;
        short8 ah[4], al[4];
        #pragma unroll
        for(int i=0;i<4;i++){
            ah[i] = *(const short8*)(As_hi + (16*i + ml)*LDS_K + k0);
            al[i] = *(const short8*)(As_lo + (16*i + ml)*LDS_K + k0);
        }
        #pragma unroll
        for(int j=0;j<2;j++){
            int nrow = j*64 + wave*16 + ml;
            short8 bh = *(const short8*)(Bh0 + nrow*LDS_K + k0);
            short8 blo = *(const short8*)(Bl0 + nrow*LDS_K + k0);
            #pragma unroll
            for(int i=0;i<4;i++){
                accL[i][j] = __builtin_amdgcn_mfma_f32_16x16x32_bf16(ah[i], bh,  accL[i][j], 0,0,0);
                accL[i][j] = __builtin_amdgcn_mfma_f32_16x16x32_bf16(ah[i], blo, accL[i][j], 0,0,0);
                accL[i][j] = __builtin_amdgcn_mfma_f32_16x16x32_bf16(al[i], bh,  accL[i][j], 0,0,0);
            }
            if(PAIR){
                short8 ch = *(const short8*)(Bh1 + nrow*LDS_K + k0);
                short8 cl = *(const short8*)(Bl1 + nrow*LDS_K + k0);
                #pragma unroll
                for(int i=0;i<4;i++){
                    accR[i][j] = __builtin_amdgcn_mfma_f32_16x16x32_bf16(ah[i], ch, accR[i][j], 0,0,0);
                    accR[i][j] = __builtin_amdgcn_mfma_f32_16x16x32_bf16(ah[i], cl, accR[i][j], 0,0,0);
                    accR[i][j] = __builtin_amdgcn_mfma_f32_16x16x32_bf16(al[i], ch, accR[i][j], 0,0,0);
                }
            }
        }
    }

    int col0 = wave*16 + ml, col1 = 64 + wave*16 + ml;
    float bL0 = bl[col0], bL1 = bl[col1];

    if(NORM){
        #pragma unroll
        for(int i=0;i<4;i++){
            #pragma unroll
            for(int rr=0;rr<4;rr++){
                float v0 = accL[i][0][rr] + bL0;
                float v1 = accL[i][1][rr] + bL1;
                float p = v0*v0 + v1*v1;
                p += __shfl_xor(p,1); p += __shfl_xor(p,2);
                p += __shfl_xor(p,4); p += __shfl_xor(p,8);
                if(ml==0) ssq[wave*64 + 16*i + quad*4 + rr] = p;
            }
        }
        __syncthreads();
        #pragma unroll
        for(int i=0;i<4;i++){
            #pragma unroll
            for(int rr=0;rr<4;rr++){
                int row = 16*i + quad*4 + rr;
                int grr = rbase + row;
                if(grr < N_NODES){
                    float tot = ssq[row] + ssq[64+row] + ssq[128+row] + ssq[192+row];
                    float inv = 1.0f / fmaxf(sqrtf(tot), 1e-12f);
                    XL[(size_t)grr*HC_DIM + col0] = (accL[i][0][rr] + bL0) * inv;
                    XL[(size_t)grr*HC_DIM + col1] = (accL[i][1][rr] + bL1) * inv;
                }
            }
        }
    } else {
        float bR0 = PAIR ? br[col0] : 0.f, bR1 = PAIR ? br[col1] : 0.f;
        #pragma unroll
        for(int i=0;i<4;i++){
            #pragma unroll
            for(int rr=0;rr<4;rr++){
                int grr = rbase + 16*i + quad*4 + rr;
                if(grr < N_NODES){
                    XL[(size_t)grr*HC_DIM + col0] = accL[i][0][rr] + bL0;
                    XL[(size_t)grr*HC_DIM + col1] = accL[i][1][rr] + bL1;
                    if(PAIR){
                        XR16[(size_t)grr*HC_DIM + col0] = f2h(accR[i][0][rr] + bR0);
                        XR16[(size_t)grr*HC_DIM + col1] = f2h(accR[i][1][rr] + bR1);
                    }
                }
            }
        }
    }
}

// ---------------- fused per-node GATv2 — round-2-verified version (best measured: 68.6us) ----------------
// f32 XL in, fp16 XR gathers, f32 hout out + bf16 hi/lo, f32 residual in. VGPR 44, occ ~51%.
__global__ __launch_bounds__(256) void k_node(const float* __restrict__ XL, const unsigned short* __restrict__ XR,
    const int* __restrict__ rowptr, const int* __restrict__ colidx,
    const float* __restrict__ att, const float* __restrict__ bo,
    const float* __restrict__ gg, const float* __restrict__ be,
    const float* __restrict__ hold, float* __restrict__ hout,
    short* __restrict__ hi_out, short* __restrict__ lo_out)
{
    int wave=threadIdx.x>>6, lane=threadIdx.x&63;
    int node = blockIdx.x*4+wave;
    int qd = lane >> 4, cl = lane & 15;
    int c8 = cl << 3;

    // prologue: xl -> fp16, att pre-scaled by 0.6*log2e / 0.4*log2e -> fp16
    const float* xlp = XL + (size_t)node*HC_DIM + c8;
    float4 xa = *(const float4*)xlp;
    float4 xb = *(const float4*)(xlp+4);
    float xlf[8] = {xa.x,xa.y,xa.z,xa.w,xb.x,xb.y,xb.z,xb.w};
    float4 aa = *(const float4*)(att + c8);
    float4 abv = *(const float4*)(att + c8 + 4);
    float af[8] = {aa.x,aa.y,aa.z,aa.w,abv.x,abv.y,abv.z,abv.w};
    hf8 xlh, av6, av4;
    const float s6 = 0.6f*LOG2E, s4 = 0.4f*LOG2E;
    #pragma unroll
    for(int k=0;k<8;k++){
        xlh[k] = (_Float16)xlf[k];
        av6[k] = (_Float16)(af[k]*s6);
        av4[k] = (_Float16)(af[k]*s4);
    }

    int beg = rowptr[node], end = rowptr[node+1];

    #define H2(v,k) __builtin_shufflevector(v, v, 2*(k), 2*(k)+1)
    #define LOADH(j, xv) { xv = *(const hf8*)((const _Float16*)XR + ((size_t)((unsigned)(j)<<7)) + c8); }
#if defined(__has_builtin) && __has_builtin(__builtin_amdgcn_fdot2)
    #define LOGIT(xv, q) { \
        hf8 u_ = xlh + xv; \
        hf8 a_ = __builtin_bit_cast(hf8, __builtin_bit_cast(uint4v, u_) & 0x7fff7fffu); \
        float qa_ = __builtin_amdgcn_fdot2(H2(u_,0), H2(av6,0), 0.f, false); \
        float qb_ = __builtin_amdgcn_fdot2(H2(a_,0), H2(av4,0), 0.f, false); \
        qa_ = __builtin_amdgcn_fdot2(H2(u_,1), H2(av6,1), qa_, false); \
        qb_ = __builtin_amdgcn_fdot2(H2(a_,1), H2(av4,1), qb_, false); \
        qa_ = __builtin_amdgcn_fdot2(H2(u_,2), H2(av6,2), qa_, false); \
        qb_ = __builtin_amdgcn_fdot2(H2(a_,2), H2(av4,2), qb_, false); \
        qa_ = __builtin_amdgcn_fdot2(H2(u_,3), H2(av6,3), qa_, false); \
        qb_ = __builtin_amdgcn_fdot2(H2(a_,3), H2(av4,3), qb_, false); \
        q = qa_ + qb_; \
        q += __shfl_xor(q,1); q += __shfl_xor(q,2); }
#else
    #define LOGIT(xv, q) { \
        hf8 u_ = xlh + xv; \
        hf8 a_ = __builtin_bit_cast(hf8, __builtin_bit_cast(uint4v, u_) & 0x7fff7fffu); \
        q = 0.f; \
        _Pragma("unroll") \
        for(int k_=0;k_<8;k_++) q = fmaf((float)u_[k_], (float)av6[k_], fmaf((float)a_[k_], (float)av4[k_], q)); \
        q += __shfl_xor(q,1); q += __shfl_xor(q,2); }
#endif
    #define UPDATE4 { \
        float nm = fmaxf(m, fmaxf(fmaxf(q0,q1),fmaxf(q2,q3))); \
        float sc = exp2f(m-nm); \
        float e0=exp2f(q0-nm), e1=exp2f(q1-nm), e2=exp2f(q2-nm), e3=exp2f(q3-nm); \
        ls = fmaf(ls, sc, (e0+e1)+(e2+e3)); \
        _Pragma("unroll") \
        for(int k=0;k<8;k++) \
            acc[k] = fmaf(acc[k], sc, fmaf(e0,(float)x0[k], fmaf(e1,(float)x1[k], fmaf(e2,(float)x2[k], e3*(float)x3[k])))); \
        m = nm; }

    // self-loop init: only quarter 0 carries it
    hf8 xs; LOADH(node, xs)
    float qs; LOGIT(xs, qs)
    float m, ls, acc[8];
    if(qd==0){
        m = qs; ls = 1.f;
        #pragma unroll
        for(int k=0;k<8;k++) acc[k] = (float)xs[k];
    } else {
        m = -1e30f; ls = 0.f;
        #pragma unroll
        for(int k=0;k<8;k++) acc[k] = 0.f;
    }

    int P = end - beg;
    int nb = P >> 4;
    int base = beg;
    int qoff = qd << 2;
    for(int b=0; b<nb; b++, base += 16){
        int b2 = base + qoff;
        int j0 = colidx[b2], j1 = colidx[b2+1], j2 = colidx[b2+2], j3 = colidx[b2+3];
        hf8 x0,x1,x2,x3;
        LOADH(j0,x0) LOADH(j1,x1) LOADH(j2,x2) LOADH(j3,x3)
        float q0,q1,q2,q3;
        LOGIT(x0,q0) LOGIT(x1,q1) LOGIT(x2,q2) LOGIT(x3,q3)
        UPDATE4
    }
    // masked tail: up to 15 remaining edges in ONE batched update per quarter
    if(base < end){
        int b2 = base + qoff;
        int j0 = (b2  <end)? colidx[b2]   : node;
        int j1 = (b2+1<end)? colidx[b2+1] : node;
        int j2 = (b2+2<end)? colidx[b2+2] : node;
        int j3 = (b2+3<end)? colidx[b2+3] : node;
        hf8 x0,x1,x2,x3;
        LOADH(j0,x0) LOADH(j1,x1) LOADH(j2,x2) LOADH(j3,x3)
        float q0,q1,q2,q3;
        LOGIT(x0,q0) LOGIT(x1,q1) LOGIT(x2,q2) LOGIT(x3,q3)
        if(b2+1>=end) q1 = -INFINITY;
        if(b2+2>=end) q2 = -INFINITY;
        if(b2+3>=end) q3 = -INFINITY;
        if(b2 < end){   // quarter has >=1 active slot (q0 finite -> nm finite)
            UPDATE4
        }
    }
    #undef UPDATE4
    #undef LOGIT
    #undef LOADH
    #undef H2

    // merge the 4 quarter states: xor 16 then xor 32
    #pragma unroll
    for(int mk=16; mk<=32; mk<<=1){
        float mo  = __shfl_xor(m, mk);
        float lso = __shfl_xor(ls, mk);
        float ao[8];
        #pragma unroll
        for(int k=0;k<8;k++) ao[k] = __shfl_xor(acc[k], mk);
        float nm = fmaxf(m, mo);
        float s0 = exp2f(m-nm), s1 = exp2f(mo-nm);
        ls = ls*s0 + lso*s1;
        #pragma unroll
        for(int k=0;k<8;k++) acc[k] = acc[k]*s0 + ao[k]*s1;
        m = nm;
    }

    float inv = 1.0f/ls;
    float4 b0 = *(const float4*)(bo + c8);
    float4 b1 = *(const float4*)(bo + c8 + 4);
    float bof[8] = {b0.x,b0.y,b0.z,b0.w,b1.x,b1.y,b1.z,b1.w};
    float o[8];
    #pragma unroll
    for(int k=0;k<8;k++) o[k] = fmaf(acc[k], inv, bof[k]);
    float s1v = ((o[0]+o[1])+(o[2]+o[3])) + ((o[4]+o[5])+(o[6]+o[7]));
    float s2v = o[0]*o[0];
    #pragma unroll
    for(int k=1;k<8;k++) s2v = fmaf(o[k],o[k],s2v);
    #pragma unroll
    for(int mk=1;mk<16;mk<<=1){ s1v += __shfl_xor(s1v,mk); s2v += __shfl_xor(s2v,mk); }
    float mean = s1v*(1.f/128.f);
    float var  = s2v*(1.f/128.f) - mean*mean;
    float rstd = rsqrtf(var + 1e-5f);

    // each lane finalizes exactly 2 channels: ch2 = 8*cl + 2*qd (covers 0..127)
    int ch2 = c8 + (qd<<1);
    float oa = (qd&2) ? ((qd&1)? o[6] : o[4]) : ((qd&1)? o[2] : o[0]);
    float ob = (qd&2) ? ((qd&1)? o[7] : o[5]) : ((qd&1)? o[3] : o[1]);
    float2 g2  = *(const float2*)(gg + ch2);
    float2 be2 = *(const float2*)(be + ch2);
    float r0 = gelu_f(fmaf(g2.x*(oa-mean), rstd, be2.x));
    float r1 = gelu_f(fmaf(g2.y*(ob-mean), rstd, be2.y));
    if(hold){
        float2 hv = *(const float2*)(hold + (size_t)node*HC_DIM + ch2);
        r0 += hv.x; r1 += hv.y;
    }
    *(float2*)(hout + (size_t)node*HC_DIM + ch2) = make_float2(r0,r1);
    short h0,l0,h1,l1;
    split2(r0,h0,l0); split2(r1,h1,l1);
    *(short2*)(hi_out + (size_t)node*HC_DIM + ch2) = make_short2(h0,h1);
    *(short2*)(lo_out + (size_t)node*HC_DIM + ch2) = make_short2(l0,l1);
}

extern "C" void kernel_launch(void* const* d_in, const int* in_sizes, int n_in,
                              void* d_out, int out_size, void* d_ws, size_t ws_size,
                              hipStream_t stream)
{
    const float* x   = (const float*)d_in[0];
    const int*   ei  = (const int*)  d_in[1];
    const float* Win = (const float*)d_in[2];
    const float* bin = (const float*)d_in[3];
    const float *Wl[3], *bl[3], *Wr[3], *br[3], *att[3], *bo[3], *gg[3], *be[3];
    for(int i=0;i<3;i++){
        const int base = 4 + 8*i;
        Wl[i]=(const float*)d_in[base+0]; bl[i]=(const float*)d_in[base+1];
        Wr[i]=(const float*)d_in[base+2]; br[i]=(const float*)d_in[base+3];
        att[i]=(const float*)d_in[base+4]; bo[i]=(const float*)d_in[base+5];
        gg[i]=(const float*)d_in[base+6]; be[i]=(const float*)d_in[base+7];
    }
    const float* Wout=(const float*)d_in[28];
    const float* bout=(const float*)d_in[29];
    float* out = (float*)d_out;

    char* w = (char*)d_ws;
    float* hA = (float*)w;  w += (size_t)N_NODES*HC_DIM*4;
    float* hB = (float*)w;  w += (size_t)N_NODES*HC_DIM*4;
    float* XL = (float*)w;  w += (size_t)N_NODES*HC_DIM*4;
    unsigned short* XR16 = (unsigned short*)w; w += (size_t)N_NODES*HC_DIM*2;
    short* hAhi = (short*)w; w += (size_t)N_NODES*HC_DIM*2;
    short* hAlo = (short*)w; w += (size_t)N_NODES*HC_DIM*2;
    short* hBhi = (short*)w; w += (size_t)N_NODES*HC_DIM*2;
    short* hBlo = (short*)w; w += (size_t)N_NODES*HC_DIM*2;
    short* WT   = (short*)w; w += (size_t)180224*2;
    int* rowptr = (int*)w;  w += (size_t)(N_NODES+2)*4;
    int* rowfin = (int*)w;  w += (size_t)(N_NODES+2)*4;
    int* cursor = (int*)w;  w += (size_t)N_NODES*4;
    int* colidx = (int*)w;  w += (size_t)N_EDGES*4;
    int* rank   = (int*)w;  w += (size_t)N_EDGES*4;
    int* part   = (int*)w;  w += 256*4;
    int* flag   = (int*)w;  w += 64;

    const int* srcp = ei;
    const int* dstp = ei + N_EDGES;

    const short* WTl0 = WT + 0;      const short* WTr0 = WT + 8192;
    const short* WTl1 = WT + 16384;  const short* WTr1 = WT + 49152;
    const short* WTl2 = WT + 81920;  const short* WTr2 = WT + 114688;
    const short* WTo  = WT + 147456;

    // ---- prep (splitW + zero + input projection) + CSR build ----
    k_prep  <<<PREP_SPLITW+PREP_MEMSET+PREP_GEMM,256,0,stream>>>(
              Wl[0],Wr[0],Wl[1],Wr[1],Wl[2],Wr[2],Wout, WT, cursor, flag,
              x, Win, bin, hA, hAhi, hAlo);
    k_count <<<782,256, 0, stream>>>(dstp, cursor, rank);
    k_scan12<<<SCAN_NB,256,0,stream>>>(cursor, rowptr, part, flag);
    k_fill  <<<782,256, 0, stream>>>(srcp, dstp, rowptr, part, rank, colidx, rowfin);

    // ---- layer 0: hA[N,32] -> hB (no residual) ----
    k_mfma<32,true,false><<<782,256,0,stream>>>(hAhi, hAlo, WTl0, bl[0], WTr0, br[0], XL, XR16);
    k_node<<<12500,256,0,stream>>>(XL,XR16,rowfin,colidx,att[0],bo[0],gg[0],be[0],
                                   (const float*)nullptr, hB, hBhi, hBlo);

    // ---- layer 1: hB -> hA (residual hB) ----
    k_mfma<128,true,false><<<782,256,0,stream>>>(hBhi, hBlo, WTl1, bl[1], WTr1, br[1], XL, XR16);
    k_node<<<12500,256,0,stream>>>(XL,XR16,rowfin,colidx,att[1],bo[1],gg[1],be[1], hB, hA, hAhi, hAlo);

    // ---- layer 2: hA -> hB (residual hA) ----
    k_mfma<128,true,false><<<782,256,0,stream>>>(hAhi, hAlo, WTl2, bl[2], WTr2, br[2], XL, XR16);
    k_node<<<12500,256,0,stream>>>(XL,XR16,rowfin,colidx,att[2],bo[2],gg[2],be[2], hA, hB, hBhi, hBlo);

    // ---- output projection + fused row L2-normalize -> out ----
    k_mfma<128,false,true><<<782,256,0,stream>>>(hBhi, hBlo, WTo, bout, nullptr, nullptr, out, nullptr);
}

// Round 11
// 489.169 us; speedup vs baseline: 1.0620x; 1.0224x over previous
//
#include <hip/hip_runtime.h>
#include <hip/hip_bf16.h>
#include <math.h>

#define N_NODES 50000
#define N_EDGES 800000
#define IN_DIM  128
#define HC_DIM  128
#define HID_C   32
#define SCAN_NB 196   // ceil(50000/256)
#define LOG2E   1.4426950408889634f
// k_prep block ranges
#define PREP_SPLITW 22
#define PREP_MEMSET 49
#define PREP_GEMM   6250

typedef __attribute__((ext_vector_type(8))) short short8;   // 8 bf16 = 4 VGPR (MFMA A/B frag)
typedef __attribute__((ext_vector_type(4))) short short4v;
typedef __attribute__((ext_vector_type(4))) float f32x4;    // MFMA C/D frag
typedef __attribute__((ext_vector_type(2))) float f32x2;    // packed f32 pair -> v_pk_*_f32
typedef _Float16 hf8 __attribute__((ext_vector_type(8)));
typedef unsigned int uint4v __attribute__((ext_vector_type(4)));

#if defined(__has_builtin) && __has_builtin(__builtin_elementwise_fma)
#define VFMA2(a,b,c) __builtin_elementwise_fma((a),(b),(c))
#else
__device__ __forceinline__ f32x2 VFMA2(f32x2 a, f32x2 b, f32x2 c){
    f32x2 r; r[0]=fmaf(a[0],b[0],c[0]); r[1]=fmaf(a[1],b[1],c[1]); return r;
}
#endif

__device__ __forceinline__ float gelu_f(float x){
    return 0.5f*x*(1.0f + erff(x*0.7071067811865475f));
}

// fp32 -> (hi, lo) bf16 split: hi = rn(f), lo = rn(f - hi).
__device__ __forceinline__ void split2(float f, short& h, short& l){
    __hip_bfloat16 bh = __float2bfloat16(f);
    float r = f - __bfloat162float(bh);
    __hip_bfloat16 blo = __float2bfloat16(r);
    h = *reinterpret_cast<short*>(&bh);
    l = *reinterpret_cast<short*>(&blo);
}
__device__ __forceinline__ unsigned short f2h(float f){
    _Float16 h = (_Float16)f;
    return __builtin_bit_cast(unsigned short, h);
}

// ---------------- k_prep: splitW (0..21) + zero cursor/flag (22..70) + gemm_in (71..6320) ----------------
__global__ __launch_bounds__(256) void k_prep(const float* __restrict__ W0, const float* __restrict__ W1,
                                              const float* __restrict__ W2, const float* __restrict__ W3,
                                              const float* __restrict__ W4, const float* __restrict__ W5,
                                              const float* __restrict__ W6, short* __restrict__ WT,
                                              int* __restrict__ cursor, int* __restrict__ flag,
                                              const float* __restrict__ x, const float* __restrict__ Win,
                                              const float* __restrict__ bin, float* __restrict__ h,
                                              short* __restrict__ hhi, short* __restrict__ hlo){
    int bx = blockIdx.x;
    if(bx < PREP_SPLITW){
        int m, kc;
        if(bx < 2){ m = bx; kc = 0; }
        else { m = 2 + (bx-2)/4; kc = (bx-2)&3; }
        const float* src; int K; size_t off;
        switch(m){
            case 0: src=W0; K=32;  off=0;      break;
            case 1: src=W1; K=32;  off=8192;   break;
            case 2: src=W2; K=128; off=16384;  break;
            case 3: src=W3; K=128; off=49152;  break;
            case 4: src=W4; K=128; off=81920;  break;
            case 5: src=W5; K=128; off=114688; break;
            default:src=W6; K=128; off=147456; break;
        }
        short* hi = WT + off;
        short* lo = hi + (size_t)K*HC_DIM;
        #pragma unroll
        for(int i=0;i<16;i++){
            int idx = threadIdx.x + i*256;
            int k = kc*32 + (idx>>7);
            int n = idx & 127;
            float f = src[(size_t)k*HC_DIM + n];
            short hh,ll; split2(f,hh,ll);
            hi[(size_t)n*K + k] = hh;
            lo[(size_t)n*K + k] = ll;
        }
    } else if(bx < PREP_SPLITW + PREP_MEMSET){
        int base = (bx - PREP_SPLITW)*1024 + threadIdx.x;
        #pragma unroll
        for(int i=0;i<4;i++){
            int e = base + i*256;
            if(e < N_NODES) cursor[e] = 0;
        }
        if(bx == PREP_SPLITW && threadIdx.x == 0) *flag = 0;
    } else {
        int id = (bx - PREP_SPLITW - PREP_MEMSET)*256 + threadIdx.x;
        int r = id>>5, c = id&31;
        const float4* x4 = (const float4*)(x + (size_t)r*IN_DIM);
        float acc=0.f;
        #pragma unroll 8
        for(int k=0;k<IN_DIM/4;k++){
            float4 xv = x4[k];
            acc = fmaf(xv.x, Win[(4*k  )*HID_C+c], acc);
            acc = fmaf(xv.y, Win[(4*k+1)*HID_C+c], acc);
            acc = fmaf(xv.z, Win[(4*k+2)*HID_C+c], acc);
            acc = fmaf(xv.w, Win[(4*k+3)*HID_C+c], acc);
        }
        float v = gelu_f(acc + bin[c]);
        h[(size_t)r*HID_C+c] = v;
        short hh,ll; split2(v,hh,ll);
        hhi[(size_t)r*HID_C+c] = hh;
        hlo[(size_t)r*HID_C+c] = ll;
    }
}

// ---------------- CSR build ----------------
__global__ __launch_bounds__(256) void k_count(const int* __restrict__ dst, int* __restrict__ cnt,
                                               int* __restrict__ rank){
    int b = blockIdx.x*1024 + threadIdx.x;
    #pragma unroll
    for(int i=0;i<4;i++){
        int e = b + i*256;
        if(e < N_EDGES) rank[e] = atomicAdd(&cnt[dst[e]], 1);
    }
}

// scan1 + last-block-does-scan2 (threadFenceReduction pattern).
__global__ __launch_bounds__(256) void k_scan12(const int* __restrict__ cnt, int* __restrict__ rowptr,
                                                int* __restrict__ part, int* __restrict__ flag){
    __shared__ int sh[256];
    __shared__ int amLast;
    int t=threadIdx.x; int i=blockIdx.x*256+t;
    int v = (i<N_NODES)? cnt[i] : 0;
    sh[t]=v; __syncthreads();
    for(int off=1; off<256; off<<=1){
        int y = (t>=off)? sh[t-off] : 0;
        __syncthreads();
        sh[t] += y;
        __syncthreads();
    }
    if(i<N_NODES) rowptr[i] = sh[t]-v;
    if(t==255) part[blockIdx.x] = sh[255];

    __threadfence();
    if(t==0){
        int old = atomicAdd(flag, 1);
        amLast = (old == (int)gridDim.x - 1);
    }
    __syncthreads();
    if(amLast){
        __threadfence();
        volatile int* vp = part;
        int v2 = (t<SCAN_NB)? vp[t] : 0;
        sh[t]=v2; __syncthreads();
        for(int off=1; off<256; off<<=1){
            int y=(t>=off)? sh[t-off]:0;
            __syncthreads();
            sh[t]+=y;
            __syncthreads();
        }
        if(t<SCAN_NB) part[t] = sh[t]-v2;
    }
}

// fill + scan3 fused; blocks 0..195 emit finalized rowfin[].
__global__ __launch_bounds__(256) void k_fill(const int* __restrict__ src, const int* __restrict__ dst,
                                              const int* __restrict__ rowptr, const int* __restrict__ part,
                                              const int* __restrict__ rank, int* __restrict__ col,
                                              int* __restrict__ rowfin){
    int b = blockIdx.x*1024 + threadIdx.x;
    #pragma unroll
    for(int i=0;i<4;i++){
        int e = b + i*256;
        if(e < N_EDGES){
            int d = dst[e];
            col[rowptr[d] + part[d>>8] + rank[e]] = src[e];
        }
    }
    if(blockIdx.x < SCAN_NB){
        int i = blockIdx.x*256 + threadIdx.x;
        if(i < N_NODES) rowfin[i] = rowptr[i] + part[i>>8];
        if(i == 0) rowfin[N_NODES] = N_EDGES;
    }
}

// ---------------- full-width MFMA GEMM (bf16x3, ~fp32) — round-2-verified version ----------------
// XL out f32, XR out fp16. NORM fuses bias + row-L2-normalize -> final f32 out.
template<int K, bool PAIR, bool NORM>
__global__ __launch_bounds__(256) void k_mfma(const short* __restrict__ Ahi, const short* __restrict__ Alo,
                                              const short* __restrict__ WTl, const float* __restrict__ bl,
                                              const short* __restrict__ WTr, const float* __restrict__ br,
                                              float* __restrict__ XL, unsigned short* __restrict__ XR16){
    constexpr int LDS_K = 40;          // 32 + 8 pad shorts (80B rows)
    constexpr int NCH = K / 32;
    __shared__ short As_hi[64*LDS_K], As_lo[64*LDS_K];
    __shared__ short Bh0[128*LDS_K], Bl0[128*LDS_K];
    __shared__ short Bh1[PAIR?128*LDS_K:1], Bl1[PAIR?128*LDS_K:1];
    __shared__ float ssq[NORM?256:1];

    int t = threadIdx.x;
    int lane = t & 63, wave = t >> 6;
    int quad = lane >> 4, ml = lane & 15;
    int rbase = blockIdx.x * 64;

    const short* WTl_lo = WTl + (size_t)K*HC_DIM;
    const short* WTr_lo = PAIR ? (WTr + (size_t)K*HC_DIM) : nullptr;

    f32x4 accL[4][2], accR[4][2];
    #pragma unroll
    for(int i=0;i<4;i++)
        #pragma unroll
        for(int j=0;j<2;j++){ accL[i][j]=(f32x4){0,0,0,0}; accR[i][j]=(f32x4){0,0,0,0}; }

    int r = t >> 2, seg = t & 3;
    int gr = rbase + r; if(gr >= N_NODES) gr = N_NODES-1;

    for(int c=0; c<NCH; c++){
        if(c) __syncthreads();
        size_t ka = (size_t)gr*K + c*32 + seg*8;
        *(short8*)(As_hi + r*LDS_K + seg*8) = *(const short8*)(Ahi + ka);
        *(short8*)(As_lo + r*LDS_K + seg*8) = *(const short8*)(Alo + ka);
        #pragma unroll
        for(int u=0; u<2; u++){
            int uu = t + u*256;
            int n = uu >> 2, sg = uu & 3;
            size_t kw = (size_t)n*K + c*32 + sg*8;
            *(short8*)(Bh0 + n*LDS_K + sg*8) = *(const short8*)(WTl + kw);
            *(short8*)(Bl0 + n*LDS_K + sg*8) = *(const short8*)(WTl_lo + kw);
            if(PAIR){
                *(short8*)(Bh1 + n*LDS_K + sg*8) = *(const short8*)(WTr + kw);
                *(short8*)(Bl1 + n*LDS_K + sg*8) = *(const short8*)(WTr_lo + kw);
            }
        }
        __syncthreads();

        int k0 = quad*8;
        short8 ah[4], al[4];
        #pragma unroll
        for(int i=0;i<4;i++){
            ah[i] = *(const short8*)(As_hi + (16*i + ml)*LDS_K + k0);
            al[i] = *(const short8*)(As_lo + (16*i + ml)*LDS_K + k0);
        }
        #pragma unroll
        for(int j=0;j<2;j++){
            int nrow = j*64 + wave*16 + ml;
            short8 bh = *(const short8*)(Bh0 + nrow*LDS_K + k0);
            short8 blo = *(const short8*)(Bl0 + nrow*LDS_K + k0);
            #pragma unroll
            for(int i=0;i<4;i++){
                accL[i][j] = __builtin_amdgcn_mfma_f32_16x16x32_bf16(ah[i], bh,  accL[i][j], 0,0,0);
                accL[i][j] = __builtin_amdgcn_mfma_f32_16x16x32_bf16(ah[i], blo, accL[i][j], 0,0,0);
                accL[i][j] = __builtin_amdgcn_mfma_f32_16x16x32_bf16(al[i], bh,  accL[i][j], 0,0,0);
            }
            if(PAIR){
                short8 ch = *(const short8*)(Bh1 + nrow*LDS_K + k0);
                short8 cl = *(const short8*)(Bl1 + nrow*LDS_K + k0);
                #pragma unroll
                for(int i=0;i<4;i++){
                    accR[i][j] = __builtin_amdgcn_mfma_f32_16x16x32_bf16(ah[i], ch, accR[i][j], 0,0,0);
                    accR[i][j] = __builtin_amdgcn_mfma_f32_16x16x32_bf16(ah[i], cl, accR[i][j], 0,0,0);
                    accR[i][j] = __builtin_amdgcn_mfma_f32_16x16x32_bf16(al[i], ch, accR[i][j], 0,0,0);
                }
            }
        }
    }

    int col0 = wave*16 + ml, col1 = 64 + wave*16 + ml;
    float bL0 = bl[col0], bL1 = bl[col1];

    if(NORM){
        #pragma unroll
        for(int i=0;i<4;i++){
            #pragma unroll
            for(int rr=0;rr<4;rr++){
                float v0 = accL[i][0][rr] + bL0;
                float v1 = accL[i][1][rr] + bL1;
                float p = v0*v0 + v1*v1;
                p += __shfl_xor(p,1); p += __shfl_xor(p,2);
                p += __shfl_xor(p,4); p += __shfl_xor(p,8);
                if(ml==0) ssq[wave*64 + 16*i + quad*4 + rr] = p;
            }
        }
        __syncthreads();
        #pragma unroll
        for(int i=0;i<4;i++){
            #pragma unroll
            for(int rr=0;rr<4;rr++){
                int row = 16*i + quad*4 + rr;
                int grr = rbase + row;
                if(grr < N_NODES){
                    float tot = ssq[row] + ssq[64+row] + ssq[128+row] + ssq[192+row];
                    float inv = 1.0f / fmaxf(sqrtf(tot), 1e-12f);
                    XL[(size_t)grr*HC_DIM + col0] = (accL[i][0][rr] + bL0) * inv;
                    XL[(size_t)grr*HC_DIM + col1] = (accL[i][1][rr] + bL1) * inv;
                }
            }
        }
    } else {
        float bR0 = PAIR ? br[col0] : 0.f, bR1 = PAIR ? br[col1] : 0.f;
        #pragma unroll
        for(int i=0;i<4;i++){
            #pragma unroll
            for(int rr=0;rr<4;rr++){
                int grr = rbase + 16*i + quad*4 + rr;
                if(grr < N_NODES){
                    XL[(size_t)grr*HC_DIM + col0] = accL[i][0][rr] + bL0;
                    XL[(size_t)grr*HC_DIM + col1] = accL[i][1][rr] + bL1;
                    if(PAIR){
                        XR16[(size_t)grr*HC_DIM + col0] = f2h(accR[i][0][rr] + bR0);
                        XR16[(size_t)grr*HC_DIM + col1] = f2h(accR[i][1][rr] + bR1);
                    }
                }
            }
        }
    }
}

// ---------------- fused per-node GATv2 — r17: packed-f32 accumulator (v_pk_fma_f32) ----------------
// Identical interface/shape to the round-2-verified best (f32 XL, fp16 XR, f32 hout, 12500
// blocks, VGPR ~44). Only change: acc/merge/epilogue math rewritten on f32x2 ext-vectors
// with __builtin_elementwise_fma — bit-identical per-element operation sequence, but lets
// ISel emit v_pk_fma_f32/v_pk_mul_f32 (gfx90a+ packed f32, dual-rate) halving those blocks.
__global__ __launch_bounds__(256) void k_node(const float* __restrict__ XL, const unsigned short* __restrict__ XR,
    const int* __restrict__ rowptr, const int* __restrict__ colidx,
    const float* __restrict__ att, const float* __restrict__ bo,
    const float* __restrict__ gg, const float* __restrict__ be,
    const float* __restrict__ hold, float* __restrict__ hout,
    short* __restrict__ hi_out, short* __restrict__ lo_out)
{
    int wave=threadIdx.x>>6, lane=threadIdx.x&63;
    int node = blockIdx.x*4+wave;
    int qd = lane >> 4, cl = lane & 15;
    int c8 = cl << 3;

    // prologue: xl -> fp16, att pre-scaled by 0.6*log2e / 0.4*log2e -> fp16
    const float* xlp = XL + (size_t)node*HC_DIM + c8;
    float4 xa = *(const float4*)xlp;
    float4 xb = *(const float4*)(xlp+4);
    float xlf[8] = {xa.x,xa.y,xa.z,xa.w,xb.x,xb.y,xb.z,xb.w};
    float4 aa = *(const float4*)(att + c8);
    float4 abv = *(const float4*)(att + c8 + 4);
    float af[8] = {aa.x,aa.y,aa.z,aa.w,abv.x,abv.y,abv.z,abv.w};
    hf8 xlh, av6, av4;
    const float s6 = 0.6f*LOG2E, s4 = 0.4f*LOG2E;
    #pragma unroll
    for(int k=0;k<8;k++){
        xlh[k] = (_Float16)xlf[k];
        av6[k] = (_Float16)(af[k]*s6);
        av4[k] = (_Float16)(af[k]*s4);
    }

    int beg = rowptr[node], end = rowptr[node+1];

    #define H2(v,k) __builtin_shufflevector(v, v, 2*(k), 2*(k)+1)
    #define LOADH(j, xv) { xv = *(const hf8*)((const _Float16*)XR + ((size_t)((unsigned)(j)<<7)) + c8); }
#if defined(__has_builtin) && __has_builtin(__builtin_amdgcn_fdot2)
    #define LOGIT(xv, q) { \
        hf8 u_ = xlh + xv; \
        hf8 a_ = __builtin_bit_cast(hf8, __builtin_bit_cast(uint4v, u_) & 0x7fff7fffu); \
        float qa_ = __builtin_amdgcn_fdot2(H2(u_,0), H2(av6,0), 0.f, false); \
        float qb_ = __builtin_amdgcn_fdot2(H2(a_,0), H2(av4,0), 0.f, false); \
        qa_ = __builtin_amdgcn_fdot2(H2(u_,1), H2(av6,1), qa_, false); \
        qb_ = __builtin_amdgcn_fdot2(H2(a_,1), H2(av4,1), qb_, false); \
        qa_ = __builtin_amdgcn_fdot2(H2(u_,2), H2(av6,2), qa_, false); \
        qb_ = __builtin_amdgcn_fdot2(H2(a_,2), H2(av4,2), qb_, false); \
        qa_ = __builtin_amdgcn_fdot2(H2(u_,3), H2(av6,3), qa_, false); \
        qb_ = __builtin_amdgcn_fdot2(H2(a_,3), H2(av4,3), qb_, false); \
        q = qa_ + qb_; \
        q += __shfl_xor(q,1); q += __shfl_xor(q,2); }
#else
    #define LOGIT(xv, q) { \
        hf8 u_ = xlh + xv; \
        hf8 a_ = __builtin_bit_cast(hf8, __builtin_bit_cast(uint4v, u_) & 0x7fff7fffu); \
        q = 0.f; \
        _Pragma("unroll") \
        for(int k_=0;k_<8;k_++) q = fmaf((float)u_[k_], (float)av6[k_], fmaf((float)a_[k_], (float)av4[k_], q)); \
        q += __shfl_xor(q,1); q += __shfl_xor(q,2); }
#endif
    // packed UPDATE4: same per-element fma chain as the scalar version (bit-identical),
    // expressed on f32x2 so the backend can emit v_pk_fma_f32.
    #define UPDATE4 { \
        float nm = fmaxf(m, fmaxf(fmaxf(q0,q1),fmaxf(q2,q3))); \
        float sc = exp2f(m-nm); \
        float e0=exp2f(q0-nm), e1=exp2f(q1-nm), e2=exp2f(q2-nm), e3=exp2f(q3-nm); \
        ls = fmaf(ls, sc, (e0+e1)+(e2+e3)); \
        f32x2 sc2={sc,sc}, e02={e0,e0}, e12={e1,e1}, e22={e2,e2}, e32={e3,e3}; \
        _Pragma("unroll") \
        for(int p=0;p<4;p++){ \
            f32x2 x0c={(float)x0[2*p],(float)x0[2*p+1]}; \
            f32x2 x1c={(float)x1[2*p],(float)x1[2*p+1]}; \
            f32x2 x2c={(float)x2[2*p],(float)x2[2*p+1]}; \
            f32x2 x3c={(float)x3[2*p],(float)x3[2*p+1]}; \
            acc2[p] = VFMA2(acc2[p], sc2, VFMA2(e02, x0c, VFMA2(e12, x1c, VFMA2(e22, x2c, e32*x3c)))); \
        } \
        m = nm; }

    // self-loop init: only quarter 0 carries it
    hf8 xs; LOADH(node, xs)
    float qs; LOGIT(xs, qs)
    float m, ls;
    f32x2 acc2[4];
    if(qd==0){
        m = qs; ls = 1.f;
        #pragma unroll
        for(int p=0;p<4;p++){ acc2[p][0] = (float)xs[2*p]; acc2[p][1] = (float)xs[2*p+1]; }
    } else {
        m = -1e30f; ls = 0.f;
        #pragma unroll
        for(int p=0;p<4;p++){ acc2[p][0] = 0.f; acc2[p][1] = 0.f; }
    }

    int P = end - beg;
    int nb = P >> 4;
    int base = beg;
    int qoff = qd << 2;
    for(int b=0; b<nb; b++, base += 16){
        int b2 = base + qoff;
        int j0 = colidx[b2], j1 = colidx[b2+1], j2 = colidx[b2+2], j3 = colidx[b2+3];
        hf8 x0,x1,x2,x3;
        LOADH(j0,x0) LOADH(j1,x1) LOADH(j2,x2) LOADH(j3,x3)
        float q0,q1,q2,q3;
        LOGIT(x0,q0) LOGIT(x1,q1) LOGIT(x2,q2) LOGIT(x3,q3)
        UPDATE4
    }
    // masked tail: up to 15 remaining edges in ONE batched update per quarter
    if(base < end){
        int b2 = base + qoff;
        int j0 = (b2  <end)? colidx[b2]   : node;
        int j1 = (b2+1<end)? colidx[b2+1] : node;
        int j2 = (b2+2<end)? colidx[b2+2] : node;
        int j3 = (b2+3<end)? colidx[b2+3] : node;
        hf8 x0,x1,x2,x3;
        LOADH(j0,x0) LOADH(j1,x1) LOADH(j2,x2) LOADH(j3,x3)
        float q0,q1,q2,q3;
        LOGIT(x0,q0) LOGIT(x1,q1) LOGIT(x2,q2) LOGIT(x3,q3)
        if(b2+1>=end) q1 = -INFINITY;
        if(b2+2>=end) q2 = -INFINITY;
        if(b2+3>=end) q3 = -INFINITY;
        if(b2 < end){   // quarter has >=1 active slot (q0 finite -> nm finite)
            UPDATE4
        }
    }
    #undef UPDATE4
    #undef LOGIT
    #undef LOADH
    #undef H2

    // merge the 4 quarter states: xor 16 then xor 32 (packed rescale)
    #pragma unroll
    for(int mk=16; mk<=32; mk<<=1){
        float mo  = __shfl_xor(m, mk);
        float lso = __shfl_xor(ls, mk);
        f32x2 ao[4];
        #pragma unroll
        for(int p=0;p<4;p++){ ao[p][0] = __shfl_xor(acc2[p][0], mk); ao[p][1] = __shfl_xor(acc2[p][1], mk); }
        float nm = fmaxf(m, mo);
        float s0 = exp2f(m-nm), s1 = exp2f(mo-nm);
        ls = ls*s0 + lso*s1;
        f32x2 s02={s0,s0}, s12={s1,s1};
        #pragma unroll
        for(int p=0;p<4;p++) acc2[p] = acc2[p]*s02 + ao[p]*s12;
        m = nm;
    }

    float inv = 1.0f/ls;
    float4 b0 = *(const float4*)(bo + c8);
    float4 b1 = *(const float4*)(bo + c8 + 4);
    f32x2 bof2[4] = {{b0.x,b0.y},{b0.z,b0.w},{b1.x,b1.y},{b1.z,b1.w}};
    f32x2 inv2 = {inv, inv};
    f32x2 o2[4];
    #pragma unroll
    for(int p=0;p<4;p++) o2[p] = VFMA2(acc2[p], inv2, bof2[p]);
    float o[8];
    #pragma unroll
    for(int p=0;p<4;p++){ o[2*p] = o2[p][0]; o[2*p+1] = o2[p][1]; }
    float s1v = ((o[0]+o[1])+(o[2]+o[3])) + ((o[4]+o[5])+(o[6]+o[7]));
    float s2v = o[0]*o[0];
    #pragma unroll
    for(int k=1;k<8;k++) s2v = fmaf(o[k],o[k],s2v);
    #pragma unroll
    for(int mk=1;mk<16;mk<<=1){ s1v += __shfl_xor(s1v,mk); s2v += __shfl_xor(s2v,mk); }
    float mean = s1v*(1.f/128.f);
    float var  = s2v*(1.f/128.f) - mean*mean;
    float rstd = rsqrtf(var + 1e-5f);

    // each lane finalizes exactly 2 channels: ch2 = 8*cl + 2*qd (covers 0..127)
    int ch2 = c8 + (qd<<1);
    float oa = (qd&2) ? ((qd&1)? o[6] : o[4]) : ((qd&1)? o[2] : o[0]);
    float ob = (qd&2) ? ((qd&1)? o[7] : o[5]) : ((qd&1)? o[3] : o[1]);
    float2 g2  = *(const float2*)(gg + ch2);
    float2 be2 = *(const float2*)(be + ch2);
    float r0 = gelu_f(fmaf(g2.x*(oa-mean), rstd, be2.x));
    float r1 = gelu_f(fmaf(g2.y*(ob-mean), rstd, be2.y));
    if(hold){
        float2 hv = *(const float2*)(hold + (size_t)node*HC_DIM + ch2);
        r0 += hv.x; r1 += hv.y;
    }
    *(float2*)(hout + (size_t)node*HC_DIM + ch2) = make_float2(r0,r1);
    short h0,l0,h1,l1;
    split2(r0,h0,l0); split2(r1,h1,l1);
    *(short2*)(hi_out + (size_t)node*HC_DIM + ch2) = make_short2(h0,h1);
    *(short2*)(lo_out + (size_t)node*HC_DIM + ch2) = make_short2(l0,l1);
}

extern "C" void kernel_launch(void* const* d_in, const int* in_sizes, int n_in,
                              void* d_out, int out_size, void* d_ws, size_t ws_size,
                              hipStream_t stream)
{
    const float* x   = (const float*)d_in[0];
    const int*   ei  = (const int*)  d_in[1];
    const float* Win = (const float*)d_in[2];
    const float* bin = (const float*)d_in[3];
    const float *Wl[3], *bl[3], *Wr[3], *br[3], *att[3], *bo[3], *gg[3], *be[3];
    for(int i=0;i<3;i++){
        const int base = 4 + 8*i;
        Wl[i]=(const float*)d_in[base+0]; bl[i]=(const float*)d_in[base+1];
        Wr[i]=(const float*)d_in[base+2]; br[i]=(const float*)d_in[base+3];
        att[i]=(const float*)d_in[base+4]; bo[i]=(const float*)d_in[base+5];
        gg[i]=(const float*)d_in[base+6]; be[i]=(const float*)d_in[base+7];
    }
    const float* Wout=(const float*)d_in[28];
    const float* bout=(const float*)d_in[29];
    float* out = (float*)d_out;

    char* w = (char*)d_ws;
    float* hA = (float*)w;  w += (size_t)N_NODES*HC_DIM*4;
    float* hB = (float*)w;  w += (size_t)N_NODES*HC_DIM*4;
    float* XL = (float*)w;  w += (size_t)N_NODES*HC_DIM*4;
    unsigned short* XR16 = (unsigned short*)w; w += (size_t)N_NODES*HC_DIM*2;
    short* hAhi = (short*)w; w += (size_t)N_NODES*HC_DIM*2;
    short* hAlo = (short*)w; w += (size_t)N_NODES*HC_DIM*2;
    short* hBhi = (short*)w; w += (size_t)N_NODES*HC_DIM*2;
    short* hBlo = (short*)w; w += (size_t)N_NODES*HC_DIM*2;
    short* WT   = (short*)w; w += (size_t)180224*2;
    int* rowptr = (int*)w;  w += (size_t)(N_NODES+2)*4;
    int* rowfin = (int*)w;  w += (size_t)(N_NODES+2)*4;
    int* cursor = (int*)w;  w += (size_t)N_NODES*4;
    int* colidx = (int*)w;  w += (size_t)N_EDGES*4;
    int* rank   = (int*)w;  w += (size_t)N_EDGES*4;
    int* part   = (int*)w;  w += 256*4;
    int* flag   = (int*)w;  w += 64;

    const int* srcp = ei;
    const int* dstp = ei + N_EDGES;

    const short* WTl0 = WT + 0;      const short* WTr0 = WT + 8192;
    const short* WTl1 = WT + 16384;  const short* WTr1 = WT + 49152;
    const short* WTl2 = WT + 81920;  const short* WTr2 = WT + 114688;
    const short* WTo  = WT + 147456;

    // ---- prep (splitW + zero + input projection) + CSR build ----
    k_prep  <<<PREP_SPLITW+PREP_MEMSET+PREP_GEMM,256,0,stream>>>(
              Wl[0],Wr[0],Wl[1],Wr[1],Wl[2],Wr[2],Wout, WT, cursor, flag,
              x, Win, bin, hA, hAhi, hAlo);
    k_count <<<782,256, 0, stream>>>(dstp, cursor, rank);
    k_scan12<<<SCAN_NB,256,0,stream>>>(cursor, rowptr, part, flag);
    k_fill  <<<782,256, 0, stream>>>(srcp, dstp, rowptr, part, rank, colidx, rowfin);

    // ---- layer 0: hA[N,32] -> hB (no residual) ----
    k_mfma<32,true,false><<<782,256,0,stream>>>(hAhi, hAlo, WTl0, bl[0], WTr0, br[0], XL, XR16);
    k_node<<<12500,256,0,stream>>>(XL,XR16,rowfin,colidx,att[0],bo[0],gg[0],be[0],
                                   (const float*)nullptr, hB, hBhi, hBlo);

    // ---- layer 1: hB -> hA (residual hB) ----
    k_mfma<128,true,false><<<782,256,0,stream>>>(hBhi, hBlo, WTl1, bl[1], WTr1, br[1], XL, XR16);
    k_node<<<12500,256,0,stream>>>(XL,XR16,rowfin,colidx,att[1],bo[1],gg[1],be[1], hB, hA, hAhi, hAlo);

    // ---- layer 2: hA -> hB (residual hA) ----
    k_mfma<128,true,false><<<782,256,0,stream>>>(hAhi, hAlo, WTl2, bl[2], WTr2, br[2], XL, XR16);
    k_node<<<12500,256,0,stream>>>(XL,XR16,rowfin,colidx,att[2],bo[2],gg[2],be[2], hA, hB, hBhi, hBlo);

    // ---- output projection + fused row L2-normalize -> out ----
    k_mfma<128,false,true><<<782,256,0,stream>>>(hBhi, hBlo, WTo, bout, nullptr, nullptr, out, nullptr);
}